// Round 8
// baseline (490.583 us; speedup 1.0000x reference)
//
#include <hip/hip_runtime.h>

#define CDIM 768
#define BATCH 8
#define LDEPTH 8
#define HHEIGHT 14
#define WWIDTH 14
#define NSP 1568      // 8*14*14 spatial tokens (input / q)
#define NQTOK 1569    // +cls
#define NKSP 392      // 8*7*7 spatial tokens (k/v after pool)
#define NKTOK 393
#define NHEADS 12
#define HEADDIM 64
#define ATTN_SCALE 0.125f
#define LN_EPS 1e-6f
#define MTOK (BATCH * NQTOK)   // 12552 tokens for proj GEMM
#define NPAD_X 1664            // Xt padded rows per batch (13 tiles * 128)
#define WELEM (CDIM * CDIM)    // 589824
#define TQP 1664               // padded q tokens per (b,h)  (13*128)
#define TKP 448                // padded kv tokens per (b,h) (7*64)

typedef _Float16 f16;
typedef _Float16 f16x8_t __attribute__((ext_vector_type(8)));
typedef _Float16 f16x4_t __attribute__((ext_vector_type(4)));
typedef float f32x4_t __attribute__((ext_vector_type(4)));

// global -> LDS direct 16B copy (wave-uniform LDS base + lane*16)
__device__ __forceinline__ void gld_lds16(const void* g, void* l) {
  __builtin_amdgcn_global_load_lds(
      (const __attribute__((address_space(1))) void*)g,
      (__attribute__((address_space(3))) void*)l, 16, 0, 0);
}

// ---------------------------------------------------------------------------
// fp32 -> fp16 convert for the 4 weight matrices (one launch, grid.y = mat)
// ---------------------------------------------------------------------------
__global__ __launch_bounds__(256) void convert4_kernel(
    const float* __restrict__ s0, const float* __restrict__ s1,
    const float* __restrict__ s2, const float* __restrict__ s3,
    f16* __restrict__ dst) {
  const int mat = blockIdx.y;
  const float* src = (mat == 0) ? s0 : (mat == 1) ? s1 : (mat == 2) ? s2 : s3;
  int i = (blockIdx.x * 256 + threadIdx.x) * 4;
  if (i < WELEM) {
    float4 v = *(const float4*)&src[i];
    f16x4_t h = {(f16)v.x, (f16)v.y, (f16)v.z, (f16)v.w};
    *(f16x4_t*)&dst[(size_t)mat * WELEM + i] = h;
  }
}

// ---------------------------------------------------------------------------
// Transpose+convert X: (B,768,1568) f32 -> Xt (B,1664,768) f16, pad rows = 0.
// ---------------------------------------------------------------------------
__global__ __launch_bounds__(256) void transpose_x_kernel(
    const float* __restrict__ X, f16* __restrict__ Xt) {
  __shared__ float t[32][33];
  const int b = blockIdx.z;
  const int k0 = blockIdx.y * 32;
  const int n0 = blockIdx.x * 32;
  const int tx = threadIdx.x & 31, ty = threadIdx.x >> 5;
#pragma unroll
  for (int i = 0; i < 4; i++) {
    int k = k0 + ty + i * 8;
    int n = n0 + tx;
    t[ty + i * 8][tx] = (n < NSP) ? X[((size_t)b * CDIM + k) * NSP + n] : 0.f;
  }
  __syncthreads();
#pragma unroll
  for (int i = 0; i < 4; i++) {
    int n = n0 + ty + i * 8;
    Xt[((size_t)b * NPAD_X + n) * CDIM + k0 + tx] = (f16)t[tx][ty + i * 8];
  }
}

// ---------------------------------------------------------------------------
// Fused QKV MFMA GEMM: double-buffered global_load_lds pipeline.
// One barrier per K-step; next tile's loads issued before current compute.
// 1D grid 1872, XCD swizzle: batch = bid&7.
// ---------------------------------------------------------------------------
__global__ __launch_bounds__(256) void gemm_qkv_f16_kernel(
    const f16* __restrict__ W16, const f16* __restrict__ Xt,
    const float* __restrict__ bq, const float* __restrict__ bk,
    const float* __restrict__ bv, f16* __restrict__ OutBase) {
  __shared__ __align__(16) f16 Asm[2][128 * 32];
  __shared__ __align__(16) f16 Bsm[2][128 * 32];

  const int bid = blockIdx.x;
  const int b = bid & 7;          // batch, XCD-contiguous
  const int rem = bid >> 3;       // 0..233
  const int ytile = rem / 13;     // 0..17
  const int n0 = (rem % 13) * 128;
  const int mat = ytile / 6;
  const int m0 = (ytile % 6) * 128;
  const int tid = threadIdx.x;
  const int lane = tid & 63;
  const int w = tid >> 6;
  const int wr = w >> 1, wc = w & 1;
  const int l15 = lane & 15, l4 = lane >> 4;

  const f16* A16 = W16 + (size_t)mat * WELEM;
  const float* bias = (mat == 0) ? bq : (mat == 1) ? bk : bv;
  f16* Out = OutBase + (size_t)mat * ((size_t)BATCH * CDIM * NSP);

  // staging: wave w covers rows [w*32, w*32+32); lane -> row w*32 + (lane>>2),
  // k-chunk (lane&3)*8. Two instrs per operand (rows +0 / +16).
  const int srow = w * 32 + (lane >> 2);
  const int skq = (lane & 3) * 8;
  const f16* Ag = A16 + (size_t)(m0 + srow) * CDIM + skq;
  const f16* Bg = Xt + ((size_t)b * NPAD_X + n0 + srow) * CDIM + skq;
  const int lofs = w * 32 * 32;

  f32x4_t acc[4][4];
#pragma unroll
  for (int i = 0; i < 4; i++)
#pragma unroll
    for (int j = 0; j < 4; j++) acc[i][j] = (f32x4_t){0.f, 0.f, 0.f, 0.f};

  // prologue: stage K-step 0 into buf 0
  gld_lds16(Ag, Asm[0] + lofs);
  gld_lds16(Ag + 16 * CDIM, Asm[0] + lofs + 16 * 32);
  gld_lds16(Bg, Bsm[0] + lofs);
  gld_lds16(Bg + 16 * CDIM, Bsm[0] + lofs + 16 * 32);
  __syncthreads();

  int cur = 0;
  for (int t = 0; t < CDIM / 32; ++t) {
    // issue next K-step's loads into the other buffer (overlap with MFMA)
    if (t + 1 < CDIM / 32) {
      const int k1 = (t + 1) * 32;
      gld_lds16(Ag + k1, Asm[cur ^ 1] + lofs);
      gld_lds16(Ag + 16 * CDIM + k1, Asm[cur ^ 1] + lofs + 16 * 32);
      gld_lds16(Bg + k1, Bsm[cur ^ 1] + lofs);
      gld_lds16(Bg + 16 * CDIM + k1, Bsm[cur ^ 1] + lofs + 16 * 32);
    }
    const f16* As = Asm[cur];
    const f16* Bs = Bsm[cur];
    f16x8_t af[4], bf[4];
#pragma unroll
    for (int mi = 0; mi < 4; mi++)
      af[mi] = *(const f16x8_t*)(As + (wr * 64 + mi * 16 + l15) * 32 + l4 * 8);
#pragma unroll
    for (int ni = 0; ni < 4; ni++)
      bf[ni] = *(const f16x8_t*)(Bs + (wc * 64 + ni * 16 + l15) * 32 + l4 * 8);
#pragma unroll
    for (int mi = 0; mi < 4; mi++)
#pragma unroll
      for (int ni = 0; ni < 4; ni++)
        acc[mi][ni] = __builtin_amdgcn_mfma_f32_16x16x32_f16(
            af[mi], bf[ni], acc[mi][ni], 0, 0, 0);
    __syncthreads();   // drains vmcnt (next buf ready) + lgkm (reads done)
    cur ^= 1;
  }

#pragma unroll
  for (int mi = 0; mi < 4; mi++) {
    const int mbase = m0 + wr * 64 + mi * 16 + l4 * 4;
#pragma unroll
    for (int ni = 0; ni < 4; ni++) {
      const int n = n0 + wc * 64 + ni * 16 + l15;
      if (n < NSP) {
#pragma unroll
        for (int r = 0; r < 4; r++) {
          Out[((size_t)b * CDIM + mbase + r) * NSP + n] =
              (f16)(acc[mi][ni][r] + bias[mbase + r]);
        }
      }
    }
  }
}

// ---------------------------------------------------------------------------
// Projection MFMA GEMM, double-buffered pipeline. 1D grid 594, bijective XCD
// swizzle.
// ---------------------------------------------------------------------------
__global__ __launch_bounds__(256) void gemm_proj_f16_kernel(
    const f16* __restrict__ Wp16, const f16* __restrict__ o16,
    const float* __restrict__ bias, float* __restrict__ xo,
    float* __restrict__ cls_o) {
  __shared__ __align__(16) f16 Asm[2][128 * 32];
  __shared__ __align__(16) f16 Bsm[2][128 * 32];

  // bijective XCD remap: nwg=594, q=74, r=2
  const int bid = blockIdx.x;
  const int xcd = bid & 7, pos_ = bid >> 3;
  const int base = (xcd < 2) ? xcd * 75 : 150 + (xcd - 2) * 74;
  const int wgid = base + pos_;
  const int m0 = (wgid / 99) * 128;
  const int n0 = (wgid % 99) * 128;
  const int tid = threadIdx.x;
  const int lane = tid & 63;
  const int w = tid >> 6;
  const int wr = w >> 1, wc = w & 1;
  const int l15 = lane & 15, l4 = lane >> 4;

  const int srow = w * 32 + (lane >> 2);
  const int skq = (lane & 3) * 8;
  const f16* Ag = Wp16 + (size_t)(m0 + srow) * CDIM + skq;
  const f16* Bg = o16 + (size_t)(n0 + srow) * CDIM + skq;
  const int lofs = w * 32 * 32;

  f32x4_t acc[4][4];
#pragma unroll
  for (int i = 0; i < 4; i++)
#pragma unroll
    for (int j = 0; j < 4; j++) acc[i][j] = (f32x4_t){0.f, 0.f, 0.f, 0.f};

  gld_lds16(Ag, Asm[0] + lofs);
  gld_lds16(Ag + 16 * CDIM, Asm[0] + lofs + 16 * 32);
  gld_lds16(Bg, Bsm[0] + lofs);
  gld_lds16(Bg + 16 * CDIM, Bsm[0] + lofs + 16 * 32);
  __syncthreads();

  int cur = 0;
  for (int t = 0; t < CDIM / 32; ++t) {
    if (t + 1 < CDIM / 32) {
      const int k1 = (t + 1) * 32;
      gld_lds16(Ag + k1, Asm[cur ^ 1] + lofs);
      gld_lds16(Ag + 16 * CDIM + k1, Asm[cur ^ 1] + lofs + 16 * 32);
      gld_lds16(Bg + k1, Bsm[cur ^ 1] + lofs);
      gld_lds16(Bg + 16 * CDIM + k1, Bsm[cur ^ 1] + lofs + 16 * 32);
    }
    const f16* As = Asm[cur];
    const f16* Bs = Bsm[cur];
    f16x8_t af[4], bf[4];
#pragma unroll
    for (int mi = 0; mi < 4; mi++)
      af[mi] = *(const f16x8_t*)(As + (wr * 64 + mi * 16 + l15) * 32 + l4 * 8);
#pragma unroll
    for (int ni = 0; ni < 4; ni++)
      bf[ni] = *(const f16x8_t*)(Bs + (wc * 64 + ni * 16 + l15) * 32 + l4 * 8);
#pragma unroll
    for (int mi = 0; mi < 4; mi++)
#pragma unroll
      for (int ni = 0; ni < 4; ni++)
        acc[mi][ni] = __builtin_amdgcn_mfma_f32_16x16x32_f16(
            af[mi], bf[ni], acc[mi][ni], 0, 0, 0);
    __syncthreads();
    cur ^= 1;
  }

#pragma unroll
  for (int ni = 0; ni < 4; ni++) {
    const int tok = n0 + wc * 64 + ni * 16 + l15;
    if (tok < MTOK) {
      const int bb = tok / NQTOK;
      const int nn = tok % NQTOK;
#pragma unroll
      for (int mi = 0; mi < 4; mi++) {
        const int mbase = m0 + wr * 64 + mi * 16 + l4 * 4;
#pragma unroll
        for (int r = 0; r < 4; r++) {
          float v = acc[mi][ni][r] + bias[mbase + r];
          if (nn == 0)
            cls_o[bb * CDIM + mbase + r] = v;
          else
            xo[((size_t)bb * CDIM + mbase + r) * (size_t)NSP + nn - 1] = v;
        }
      }
    }
  }
}

// ---------------------------------------------------------------------------
// cls token linears (fp32), one launch: grid (B, 3)
// ---------------------------------------------------------------------------
__global__ __launch_bounds__(256) void cls_linear3_kernel(
    const float* __restrict__ cls, const float* __restrict__ Wq,
    const float* __restrict__ Wk, const float* __restrict__ Wv,
    const float* __restrict__ bq, const float* __restrict__ bk,
    const float* __restrict__ bv, float* __restrict__ out_base) {
  __shared__ float xs[CDIM];
  const int b = blockIdx.x;
  const int mat = blockIdx.y;
  const float* W = (mat == 0) ? Wq : (mat == 1) ? Wk : Wv;
  const float* bias = (mat == 0) ? bq : (mat == 1) ? bk : bv;
  float* out = out_base + (size_t)mat * BATCH * CDIM;
  for (int i = threadIdx.x; i < CDIM; i += 256) xs[i] = cls[b * CDIM + i];
  __syncthreads();
#pragma unroll
  for (int cc = 0; cc < 3; cc++) {
    int co = threadIdx.x + cc * 256;
    const float* wr = W + (size_t)co * CDIM;
    float sum = bias[co];
    for (int k = 0; k < CDIM; k += 4) {
      float4 wv = *(const float4*)&wr[k];
      float4 xv = *(const float4*)&xs[k];
      sum = fmaf(wv.x, xv.x, sum);
      sum = fmaf(wv.y, xv.y, sum);
      sum = fmaf(wv.z, xv.z, sum);
      sum = fmaf(wv.w, xv.w, sum);
    }
    out[b * CDIM + co] = sum;
  }
}

// ---------------------------------------------------------------------------
// Depthwise 3x3x3 conv, f16 in / f16 out (f32 accumulate).
// ---------------------------------------------------------------------------
__global__ __launch_bounds__(256) void dwconv_kernel(
    const f16* __restrict__ X, const float* __restrict__ wconv,
    f16* __restrict__ Out, int Lo, int Ho, int Wo, int sh, int sw) {
  __shared__ float xin[NSP];
  __shared__ float wsm[27];
  const int c = blockIdx.x % CDIM;
  const int b = blockIdx.x / CDIM;
  const f16* xb = X + ((size_t)b * CDIM + c) * (size_t)NSP;
  for (int i = threadIdx.x * 8; i < NSP; i += 2048) {
    f16x8_t v = *(const f16x8_t*)&xb[i];
#pragma unroll
    for (int j = 0; j < 8; j++) xin[i + j] = (float)v[j];
  }
  if (threadIdx.x < 27) wsm[threadIdx.x] = wconv[c * 27 + threadIdx.x];
  __syncthreads();
  const int npos = Lo * Ho * Wo;
  f16* ob = Out + ((size_t)b * CDIM + c) * (size_t)npos;
  for (int pos = threadIdx.x; pos < npos; pos += 256) {
    int wo = pos % Wo;
    int ho = (pos / Wo) % Ho;
    int lo = pos / (Wo * Ho);
    int li0 = lo - 1, hi0 = ho * sh - 1, wi0 = wo * sw - 1;
    float sum = 0.f;
#pragma unroll
    for (int kd = 0; kd < 3; kd++) {
      int li = li0 + kd;
      if (li < 0 || li >= LDEPTH) continue;
#pragma unroll
      for (int kh = 0; kh < 3; kh++) {
        int hi = hi0 + kh;
        if (hi < 0 || hi >= HHEIGHT) continue;
#pragma unroll
        for (int kw = 0; kw < 3; kw++) {
          int wi = wi0 + kw;
          if (wi < 0 || wi >= WWIDTH) continue;
          sum = fmaf(xin[(li * HHEIGHT + hi) * WWIDTH + wi],
                     wsm[(kd * 3 + kh) * 3 + kw], sum);
        }
      }
    }
    ob[pos] = (f16)sum;
  }
}

// ---------------------------------------------------------------------------
// Fused LayerNorm + head-pack for q/k (f16 in, f16 head layout out).
// ---------------------------------------------------------------------------
__global__ __launch_bounds__(256) void ln_pack_qk_kernel(
    const f16* __restrict__ xp, const float* __restrict__ ln_w,
    const float* __restrict__ ln_b, f16* __restrict__ OutH, int np, int tp) {
  const int b = blockIdx.y;
  const int p0 = blockIdx.x * 32;
  const int tid = threadIdx.x;
  const int pl = tid & 31;
  const int grp = tid >> 5;
  const int pos = p0 + pl;
  const bool act = pos < np;
  const f16* Xb = xp + (size_t)b * CDIM * (size_t)np;

  __shared__ float r1[8][33], r2[8][33];
  __shared__ float smean[32], srstd[32];
  __shared__ __align__(16) f16 tile[32][72];

  float s1 = 0.f, s2 = 0.f;
  if (act) {
    for (int c = grp; c < CDIM; c += 8) {
      float v = (float)Xb[(size_t)c * np + pos];
      s1 += v;
      s2 = fmaf(v, v, s2);
    }
  }
  r1[grp][pl] = s1;
  r2[grp][pl] = s2;
  __syncthreads();
  if (tid < 32) {
    float t1 = 0.f, t2 = 0.f;
#pragma unroll
    for (int g = 0; g < 8; g++) { t1 += r1[g][tid]; t2 += r2[g][tid]; }
    float mean = t1 * (1.f / 768.f);
    float var = t2 * (1.f / 768.f) - mean * mean;
    smean[tid] = mean;
    srstd[tid] = rsqrtf(var + LN_EPS);
  }
  __syncthreads();
  const float mean = smean[pl], rstd = srstd[pl];
  const int tl = tid >> 3, d8 = (tid & 7) * 8;

  for (int h = 0; h < NHEADS; h++) {
    f16x8_t hv;
#pragma unroll
    for (int i = 0; i < 8; i++) {
      int c = h * 64 + grp * 8 + i;
      float v = act ? (float)Xb[(size_t)c * np + pos] : 0.f;
      hv[i] = (f16)((v - mean) * rstd * ln_w[c] + ln_b[c]);
    }
    *(f16x8_t*)&tile[pl][grp * 8] = hv;
    __syncthreads();
    if (p0 + tl < np) {
      uint4 vv = *(const uint4*)&tile[tl][d8];
      *(uint4*)(OutH +
                (((size_t)(b * NHEADS + h)) * (size_t)tp + (p0 + tl + 1)) * 64 +
                d8) = vv;
    }
    __syncthreads();
  }
}

// ---------------------------------------------------------------------------
// Fused LayerNorm + transpose-pack for v (f16 input).
// ---------------------------------------------------------------------------
__global__ __launch_bounds__(256) void ln_pack_v_kernel(
    const f16* __restrict__ vp, const float* __restrict__ clsv,
    const float* __restrict__ ln_w, const float* __restrict__ ln_b,
    f16* __restrict__ Vht) {
  const int b = blockIdx.y;
  const int t0 = blockIdx.x * 32;
  const int tid = threadIdx.x;
  const int pl = tid & 31;
  const int grp = tid >> 5;
  const int t = t0 + pl;
  const int pos = t - 1;
  const bool isv = (t >= 1) && (t < NKTOK);
  const f16* Vb = vp + (size_t)b * CDIM * (size_t)NKSP;

  __shared__ float r1[8][33], r2[8][33];
  __shared__ float smean[32], srstd[32];
  __shared__ __align__(16) f16 vtile[128][40];

  float s1 = 0.f, s2 = 0.f;
  if (isv) {
    for (int c = grp; c < CDIM; c += 8) {
      float v = (float)Vb[(size_t)c * NKSP + pos];
      s1 += v;
      s2 = fmaf(v, v, s2);
    }
  }
  r1[grp][pl] = s1;
  r2[grp][pl] = s2;
  __syncthreads();
  if (tid < 32) {
    float t1 = 0.f, t2 = 0.f;
#pragma unroll
    for (int g = 0; g < 8; g++) { t1 += r1[g][tid]; t2 += r2[g][tid]; }
    float mean = t1 * (1.f / 768.f);
    float var = t2 * (1.f / 768.f) - mean * mean;
    smean[tid] = mean;
    srstd[tid] = rsqrtf(var + LN_EPS);
  }
  __syncthreads();
  const float mean = smean[pl], rstd = srstd[pl];

  for (int cc = 0; cc < 6; cc++) {
#pragma unroll
    for (int i = 0; i < 16; i++) {
      int cl = grp * 16 + i;
      int c = cc * 128 + cl;
      float outv;
      if (isv)
        outv = ((float)Vb[(size_t)c * NKSP + pos] - mean) * rstd * ln_w[c] +
               ln_b[c];
      else if (t == 0)
        outv = clsv[b * CDIM + c];
      else
        outv = 0.f;
      vtile[cl][pl] = (f16)outv;
    }
    __syncthreads();
#pragma unroll
    for (int it = 0; it < 2; it++) {
      int idx = it * 256 + tid;
      int cl = idx >> 2, t8 = (idx & 3) * 8;
      uint4 vv = *(const uint4*)&vtile[cl][t8];
      *(uint4*)(Vht + ((size_t)b * CDIM + cc * 128 + cl) * (size_t)TKP + t0 +
                t8) = vv;
    }
    __syncthreads();
  }
}

// ---------------------------------------------------------------------------
// cls_fill: write t=0 rows of Qh and Kh from cls linear outputs.
// ---------------------------------------------------------------------------
__global__ __launch_bounds__(768) void cls_fill_kernel(
    const float* __restrict__ clsq, const float* __restrict__ clsk,
    f16* __restrict__ Qh, f16* __restrict__ Kh) {
  const int b = blockIdx.x;
  const int c = threadIdx.x;
  Qh[(((size_t)(b * NHEADS + (c >> 6))) * TQP) * 64 + (c & 63)] =
      (f16)clsq[b * CDIM + c];
  Kh[(((size_t)(b * NHEADS + (c >> 6))) * TKP) * 64 + (c & 63)] =
      (f16)clsk[b * CDIM + c];
}

// ---------------------------------------------------------------------------
// MFMA flash attention. Grid (13, 12, 8), 256 threads = 4 waves.
// ---------------------------------------------------------------------------
__global__ __launch_bounds__(256) void attn_mfma_kernel(
    const f16* __restrict__ Qh, const f16* __restrict__ Kh,
    const f16* __restrict__ Vht, f16* __restrict__ o16) {
  __shared__ __align__(16) f16 Ks[64 * 72];   // [key][d], pad 8
  __shared__ __align__(16) f16 Vt[64 * 72];   // [d][key], pad 8
  const int qt = blockIdx.x, h = blockIdx.y, b = blockIdx.z;
  const int tid = threadIdx.x;
  const int lane = tid & 63;
  const int w = tid >> 6;
  const int l15 = lane & 15, l4 = lane >> 4;
  const int q0 = qt * 128 + w * 32;

  const f16* Qp = Qh + ((size_t)(b * NHEADS + h) * TQP) * 64;
  const f16* Kp = Kh + ((size_t)(b * NHEADS + h) * TKP) * 64;
  const f16* Vp = Vht + ((size_t)(b * NHEADS + h) * 64) * TKP;

  f16x8_t bq[2][2];
#pragma unroll
  for (int qi = 0; qi < 2; qi++)
#pragma unroll
    for (int kf = 0; kf < 2; kf++)
      bq[qi][kf] = *(const f16x8_t*)(Qp + (size_t)(q0 + qi * 16 + l15) * 64 +
                                     kf * 32 + l4 * 8);

  f32x4_t oacc[4][2];
#pragma unroll
  for (int df = 0; df < 4; df++)
#pragma unroll
    for (int qi = 0; qi < 2; qi++) oacc[df][qi] = (f32x4_t){0.f, 0.f, 0.f, 0.f};
  float mrow[2] = {-1e30f, -1e30f};
  float lrow[2] = {0.f, 0.f};

  const int sr = tid >> 2, sc = (tid & 3) * 16;

  for (int kv0 = 0; kv0 < TKP; kv0 += 64) {
    const f16* kg = Kp + (size_t)(kv0 + sr) * 64 + sc;
    uint4 kl0 = *(const uint4*)kg;
    uint4 kl1 = *(const uint4*)(kg + 8);
    const f16* vg = Vp + (size_t)sr * TKP + kv0 + sc;
    uint4 vl0 = *(const uint4*)vg;
    uint4 vl1 = *(const uint4*)(vg + 8);
    __syncthreads();
    *(uint4*)(Ks + sr * 72 + sc) = kl0;
    *(uint4*)(Ks + sr * 72 + sc + 8) = kl1;
    *(uint4*)(Vt + sr * 72 + sc) = vl0;
    *(uint4*)(Vt + sr * 72 + sc + 8) = vl1;
    __syncthreads();

    f32x4_t sacc[4][2];
#pragma unroll
    for (int ki = 0; ki < 4; ki++)
#pragma unroll
      for (int qi = 0; qi < 2; qi++) sacc[ki][qi] = (f32x4_t){0.f, 0.f, 0.f, 0.f};
#pragma unroll
    for (int kf = 0; kf < 2; kf++) {
#pragma unroll
      for (int ki = 0; ki < 4; ki++) {
        f16x8_t ak =
            *(const f16x8_t*)(Ks + (ki * 16 + l15) * 72 + kf * 32 + l4 * 8);
#pragma unroll
        for (int qi = 0; qi < 2; qi++)
          sacc[ki][qi] = __builtin_amdgcn_mfma_f32_16x16x32_f16(
              ak, bq[qi][kf], sacc[ki][qi], 0, 0, 0);
      }
    }

    float pmax[2] = {-1e30f, -1e30f};
#pragma unroll
    for (int ki = 0; ki < 4; ki++) {
      const int keyb = kv0 + ki * 16 + l4 * 4;
#pragma unroll
      for (int qi = 0; qi < 2; qi++) {
#pragma unroll
        for (int rr = 0; rr < 4; rr++) {
          float s = sacc[ki][qi][rr] * ATTN_SCALE;
          if (keyb + rr >= NKTOK) s = -1e30f;
          sacc[ki][qi][rr] = s;
          pmax[qi] = fmaxf(pmax[qi], s);
        }
      }
    }
#pragma unroll
    for (int qi = 0; qi < 2; qi++) {
      pmax[qi] = fmaxf(pmax[qi], __shfl_xor(pmax[qi], 16, 64));
      pmax[qi] = fmaxf(pmax[qi], __shfl_xor(pmax[qi], 32, 64));
      float mnew = fmaxf(mrow[qi], pmax[qi]);
      float alpha = __expf(mrow[qi] - mnew);
      mrow[qi] = mnew;
      lrow[qi] *= alpha;
#pragma unroll
      for (int df = 0; df < 4; df++) {
        oacc[df][qi][0] *= alpha;
        oacc[df][qi][1] *= alpha;
        oacc[df][qi][2] *= alpha;
        oacc[df][qi][3] *= alpha;
      }
    }
    f16x4_t pb[4][2];
#pragma unroll
    for (int ki = 0; ki < 4; ki++) {
#pragma unroll
      for (int qi = 0; qi < 2; qi++) {
        float p0 = __expf(sacc[ki][qi][0] - mrow[qi]);
        float p1 = __expf(sacc[ki][qi][1] - mrow[qi]);
        float p2 = __expf(sacc[ki][qi][2] - mrow[qi]);
        float p3 = __expf(sacc[ki][qi][3] - mrow[qi]);
        lrow[qi] += p0 + p1 + p2 + p3;
        f16x4_t pv = {(f16)p0, (f16)p1, (f16)p2, (f16)p3};
        pb[ki][qi] = pv;
      }
    }

#pragma unroll
    for (int df = 0; df < 4; df++) {
#pragma unroll
      for (int ki = 0; ki < 4; ki++) {
        f16x4_t av =
            *(const f16x4_t*)(Vt + (df * 16 + l15) * 72 + ki * 16 + l4 * 4);
#pragma unroll
        for (int qi = 0; qi < 2; qi++)
          oacc[df][qi] = __builtin_amdgcn_mfma_f32_16x16x16f16(
              av, pb[ki][qi], oacc[df][qi], 0, 0, 0);
      }
    }
  }

  float inv[2];
#pragma unroll
  for (int qi = 0; qi < 2; qi++) {
    float l = lrow[qi];
    l += __shfl_xor(l, 16, 64);
    l += __shfl_xor(l, 32, 64);
    inv[qi] = 1.f / l;
  }
#pragma unroll
  for (int qi = 0; qi < 2; qi++) {
    const int q = q0 + qi * 16 + l15;
    if (q < NQTOK) {
      f16* op = o16 + ((size_t)(b * NQTOK + q)) * CDIM + h * 64 + l4 * 4;
#pragma unroll
      for (int df = 0; df < 4; df++) {
        f16x4_t ov = {(f16)(oacc[df][qi][0] * inv[qi]),
                      (f16)(oacc[df][qi][1] * inv[qi]),
                      (f16)(oacc[df][qi][2] * inv[qi]),
                      (f16)(oacc[df][qi][3] * inv[qi])};
        *(f16x4_t*)(op + df * 16) = ov;
      }
    }
  }
}

// ---------------------------------------------------------------------------
extern "C" void kernel_launch(void* const* d_in, const int* in_sizes, int n_in,
                              void* d_out, int out_size, void* d_ws, size_t ws_size,
                              hipStream_t stream) {
  const float* x      = (const float*)d_in[0];
  const float* cls    = (const float*)d_in[1];
  const float* Wq     = (const float*)d_in[2];
  const float* bq     = (const float*)d_in[3];
  const float* Wk     = (const float*)d_in[4];
  const float* bk     = (const float*)d_in[5];
  const float* Wv     = (const float*)d_in[6];
  const float* bv     = (const float*)d_in[7];
  const float* conv_q = (const float*)d_in[8];
  const float* conv_k = (const float*)d_in[9];
  const float* conv_v = (const float*)d_in[10];
  const float* lnq_w  = (const float*)d_in[11];
  const float* lnq_b  = (const float*)d_in[12];
  const float* lnk_w  = (const float*)d_in[13];
  const float* lnk_b  = (const float*)d_in[14];
  const float* lnv_w  = (const float*)d_in[15];
  const float* lnv_b  = (const float*)d_in[16];
  const float* Wproj  = (const float*)d_in[17];
  const float* bproj  = (const float*)d_in[18];

  // Workspace layout (bytes), all f16 intermediates. Total ≈ 103.7 MB.
  char* wsb = (char*)d_ws;
  f16*   Xt     = (f16*)(wsb + 0);           // 20,447,232
  f16*   W16    = (f16*)(wsb + 20447232);    //  4,718,592
  f16*   q_lin  = (f16*)(wsb + 25165824);    // 19,267,584
  f16*   k_lin  = (f16*)(wsb + 44433408);    // 19,267,584
  f16*   v_lin  = (f16*)(wsb + 63700992);    // 19,267,584
  f16*   k_pool = (f16*)(wsb + 82968576);    //  4,816,896
  f16*   v_pool = (f16*)(wsb + 87785472);    //  4,816,896
  float* clsq   = (float*)(wsb + 92602368);  //  3 x 24,576 contiguous
  float* clsk   = (float*)(wsb + 92626944);
  float* clsv   = (float*)(wsb + 92651520);
  f16*   Kh     = (f16*)(wsb + 92676096);    //  5,505,024
  f16*   Vht    = (f16*)(wsb + 98181120);    //  5,505,024 -> end 103,686,144
  f16*   q_pool = k_lin;        // alias: k_lin dead after dwconv_k
  f16*   Qh     = Xt;           // alias: Xt dead after QKV GEMM
  f16*   o16    = v_lin;        // alias: v_lin (+k_pool head) dead by attn

  f16* W16p = W16 + (size_t)3 * WELEM;

  // 1. convert weights to fp16 (one launch)
  convert4_kernel<<<dim3(576, 4), 256, 0, stream>>>(Wq, Wk, Wv, Wproj, W16);

  // 2. transpose+convert X -> Xt
  transpose_x_kernel<<<dim3(52, 24, BATCH), 256, 0, stream>>>(x, Xt);

  // 3. fused QKV MFMA GEMM (double-buffered pipeline) -> f16 lin buffers
  gemm_qkv_f16_kernel<<<1872, 256, 0, stream>>>(W16, Xt, bq, bk, bv, q_lin);

  // 4. cls token linears (one launch)
  cls_linear3_kernel<<<dim3(BATCH, 3), 256, 0, stream>>>(cls, Wq, Wk, Wv, bq,
                                                         bk, bv, clsq);

  // 5. depthwise convs (k first, then q overwrites k_lin via alias)
  dwconv_kernel<<<BATCH * CDIM, 256, 0, stream>>>(k_lin, conv_k, k_pool,
                                                  8, 7, 7, 2, 2);
  dwconv_kernel<<<BATCH * CDIM, 256, 0, stream>>>(v_lin, conv_v, v_pool,
                                                  8, 7, 7, 2, 2);
  dwconv_kernel<<<BATCH * CDIM, 256, 0, stream>>>(q_lin, conv_q, q_pool,
                                                  8, 14, 14, 1, 1);

  // 6. fused LN + pack
  ln_pack_qk_kernel<<<dim3(49, BATCH), 256, 0, stream>>>(q_pool, lnq_w, lnq_b,
                                                         Qh, NSP, TQP);
  ln_pack_qk_kernel<<<dim3(13, BATCH), 256, 0, stream>>>(k_pool, lnk_w, lnk_b,
                                                         Kh, NKSP, TKP);
  ln_pack_v_kernel<<<dim3(14, BATCH), 256, 0, stream>>>(v_pool, clsv, lnv_w,
                                                        lnv_b, Vht);
  cls_fill_kernel<<<BATCH, 768, 0, stream>>>(clsq, clsk, Qh, Kh);

  // 7. MFMA attention -> o16
  attn_mfma_kernel<<<dim3(13, NHEADS, BATCH), 256, 0, stream>>>(Qh, Kh, Vht,
                                                                o16);

  // 8. projection MFMA GEMM (bijective XCD swizzle) -> d_out
  float* xo = (float*)d_out;
  float* cls_o = (float*)d_out + (size_t)BATCH * CDIM * NSP;
  gemm_proj_f16_kernel<<<594, 256, 0, stream>>>(W16p, o16, bproj, xo, cls_o);
}

// Round 9
// 355.945 us; speedup vs baseline: 1.3783x; 1.3783x over previous
//
#include <hip/hip_runtime.h>

#define CDIM 768
#define BATCH 8
#define LDEPTH 8
#define HHEIGHT 14
#define WWIDTH 14
#define NSP 1568      // 8*14*14 spatial tokens (input / q)
#define NSPX 1576     // lin-buffer row stride: NSP + cls col (1568) + pad
#define NQTOK 1569    // +cls
#define NKSP 392      // 8*7*7 spatial tokens (k/v after pool)
#define NKTOK 393
#define NHEADS 12
#define HEADDIM 64
#define ATTN_SCALE 0.125f
#define LN_EPS 1e-6f
#define MTOK (BATCH * NQTOK)   // 12552 tokens for proj GEMM
#define NPAD_X 1792            // Xt padded rows per batch (7 tiles * 256)
#define NPAD_TOK 12800         // proj padded tokens (50 tiles * 256)
#define WELEM (CDIM * CDIM)    // 589824
#define TQP 1664               // padded q tokens per (b,h)  (13*128)
#define TKP 448                // padded kv tokens per (b,h) (7*64)

typedef _Float16 f16;
typedef _Float16 f16x8_t __attribute__((ext_vector_type(8)));
typedef _Float16 f16x4_t __attribute__((ext_vector_type(4)));
typedef float f32x4_t __attribute__((ext_vector_type(4)));

// global -> LDS direct 16B copy (wave-uniform LDS base + lane*16)
__device__ __forceinline__ void gld_lds16(const void* g, void* l) {
  __builtin_amdgcn_global_load_lds(
      (const __attribute__((address_space(1))) void*)g,
      (__attribute__((address_space(3))) void*)l, 16, 0, 0);
}

// ---------------------------------------------------------------------------
// fp32 -> fp16 convert for the 4 weight matrices (one launch, grid.y = mat)
// ---------------------------------------------------------------------------
__global__ __launch_bounds__(256) void convert4_kernel(
    const float* __restrict__ s0, const float* __restrict__ s1,
    const float* __restrict__ s2, const float* __restrict__ s3,
    f16* __restrict__ dst) {
  const int mat = blockIdx.y;
  const float* src = (mat == 0) ? s0 : (mat == 1) ? s1 : (mat == 2) ? s2 : s3;
  int i = (blockIdx.x * 256 + threadIdx.x) * 4;
  if (i < WELEM) {
    float4 v = *(const float4*)&src[i];
    f16x4_t h = {(f16)v.x, (f16)v.y, (f16)v.z, (f16)v.w};
    *(f16x4_t*)&dst[(size_t)mat * WELEM + i] = h;
  }
}

// ---------------------------------------------------------------------------
// Transpose+convert X: (B,768,1568) f32 -> Xt (B,1792,768) f16.
// Row 1568 = class_token (cls joins the QKV GEMM); rows >1568 = 0.
// ---------------------------------------------------------------------------
__global__ __launch_bounds__(256) void transpose_x_kernel(
    const float* __restrict__ X, const float* __restrict__ cls,
    f16* __restrict__ Xt) {
  __shared__ float t[32][33];
  const int b = blockIdx.z;
  const int k0 = blockIdx.y * 32;
  const int n0 = blockIdx.x * 32;   // grid.x = 56 (1792/32)
  const int tx = threadIdx.x & 31, ty = threadIdx.x >> 5;
#pragma unroll
  for (int i = 0; i < 4; i++) {
    int k = k0 + ty + i * 8;
    int n = n0 + tx;
    float v;
    if (n < NSP)
      v = X[((size_t)b * CDIM + k) * NSP + n];
    else if (n == NSP)
      v = cls[b * CDIM + k];
    else
      v = 0.f;
    t[ty + i * 8][tx] = v;
  }
  __syncthreads();
#pragma unroll
  for (int i = 0; i < 4; i++) {
    int n = n0 + ty + i * 8;
    Xt[((size_t)b * NPAD_X + n) * CDIM + k0 + tx] = (f16)t[tx][ty + i * 8];
  }
}

// ---------------------------------------------------------------------------
// Fused QKV MFMA GEMM. Block tile 128(m) x 256(n), BK=32, 4 waves, wave tile
// 64x128 (acc[4][8]). global_load_lds staging with SOURCE-side XOR swizzle
// (chunk ^= (row>>1)&3) matched by read-side XOR -> 2-way (free) ds_read.
// 1D grid 1008, XCD swizzle: batch = bid&7.
// ---------------------------------------------------------------------------
__global__ __launch_bounds__(256, 2) void gemm_qkv_f16_kernel(
    const f16* __restrict__ W16, const f16* __restrict__ Xt,
    const float* __restrict__ bq, const float* __restrict__ bk,
    const float* __restrict__ bv, f16* __restrict__ OutBase) {
  __shared__ __align__(16) f16 Asm[128 * 32];   // 8 KB
  __shared__ __align__(16) f16 Bsm[256 * 32];   // 16 KB

  const int bid = blockIdx.x;
  const int b = bid & 7;            // batch, XCD-contiguous
  const int rem = bid >> 3;         // 0..125
  const int mat = rem / 42;
  const int rem2 = rem % 42;
  const int m0 = (rem2 / 7) * 128;
  const int n0 = (rem2 % 7) * 256;
  const int tid = threadIdx.x;
  const int lane = tid & 63;
  const int w = tid >> 6;
  const int wr = w >> 1, wc = w & 1;
  const int l15 = lane & 15, l4 = lane >> 4;

  const f16* A16 = W16 + (size_t)mat * WELEM;
  const float* bias = (mat == 0) ? bq : (mat == 1) ? bk : bv;
  f16* Out = OutBase + (size_t)mat * ((size_t)BATCH * CDIM * NSPX);

  // staging: source-swizzled chunk so linear LDS dest holds swizzled layout
  const int srow = lane >> 2;
  const int skq = ((lane & 3) ^ ((lane >> 3) & 3)) * 8;
  const f16* Ag = A16 + (size_t)(m0 + w * 32 + srow) * CDIM + skq;
  const f16* Bg = Xt + ((size_t)b * NPAD_X + n0 + w * 64 + srow) * CDIM + skq;
  f16* lA = Asm + w * 32 * 32;
  f16* lB = Bsm + w * 64 * 32;

  const int rsw = (l15 >> 1) & 3;   // read-side chunk XOR (matches source swz)
  const int kchunk = (l4 ^ rsw) * 8;

  f32x4_t acc[4][8];
#pragma unroll
  for (int i = 0; i < 4; i++)
#pragma unroll
    for (int j = 0; j < 8; j++) acc[i][j] = (f32x4_t){0.f, 0.f, 0.f, 0.f};

  for (int k0 = 0; k0 < CDIM; k0 += 32) {
    gld_lds16(Ag + k0, lA);
    gld_lds16(Ag + 16 * CDIM + k0, lA + 16 * 32);
    gld_lds16(Bg + k0, lB);
    gld_lds16(Bg + 16 * CDIM + k0, lB + 16 * 32);
    gld_lds16(Bg + 32 * CDIM + k0, lB + 32 * 32);
    gld_lds16(Bg + 48 * CDIM + k0, lB + 48 * 32);
    __syncthreads();
    f16x8_t af[4];
#pragma unroll
    for (int mi = 0; mi < 4; mi++)
      af[mi] = *(const f16x8_t*)(Asm + (wr * 64 + mi * 16 + l15) * 32 + kchunk);
#pragma unroll
    for (int ni = 0; ni < 8; ni++) {
      f16x8_t bfv =
          *(const f16x8_t*)(Bsm + (wc * 128 + ni * 16 + l15) * 32 + kchunk);
#pragma unroll
      for (int mi = 0; mi < 4; mi++)
        acc[mi][ni] = __builtin_amdgcn_mfma_f32_16x16x32_f16(
            af[mi], bfv, acc[mi][ni], 0, 0, 0);
    }
    __syncthreads();
  }

#pragma unroll
  for (int mi = 0; mi < 4; mi++) {
    const int mbase = m0 + wr * 64 + mi * 16 + l4 * 4;
#pragma unroll
    for (int ni = 0; ni < 8; ni++) {
      const int n = n0 + wc * 128 + ni * 16 + l15;
      if (n < NQTOK) {   // n == 1568 is the cls column
#pragma unroll
        for (int r = 0; r < 4; r++) {
          Out[((size_t)b * CDIM + mbase + r) * NSPX + n] =
              (f16)(acc[mi][ni][r] + bias[mbase + r]);
        }
      }
    }
  }
}

// ---------------------------------------------------------------------------
// Projection MFMA GEMM, same 128x256 structure. 1D grid 300, bijective XCD
// swizzle (nwg=300: q=37, r=4).
// ---------------------------------------------------------------------------
__global__ __launch_bounds__(256, 2) void gemm_proj_f16_kernel(
    const f16* __restrict__ Wp16, const f16* __restrict__ o16,
    const float* __restrict__ bias, float* __restrict__ xo,
    float* __restrict__ cls_o) {
  __shared__ __align__(16) f16 Asm[128 * 32];
  __shared__ __align__(16) f16 Bsm[256 * 32];

  const int bid = blockIdx.x;
  const int xcd = bid & 7, pos_ = bid >> 3;
  const int base = (xcd < 4) ? xcd * 38 : 152 + (xcd - 4) * 37;
  const int wgid = base + pos_;
  const int m0 = (wgid / 50) * 128;
  const int n0 = (wgid % 50) * 256;
  const int tid = threadIdx.x;
  const int lane = tid & 63;
  const int w = tid >> 6;
  const int wr = w >> 1, wc = w & 1;
  const int l15 = lane & 15, l4 = lane >> 4;

  const int srow = lane >> 2;
  const int skq = ((lane & 3) ^ ((lane >> 3) & 3)) * 8;
  const f16* Ag = Wp16 + (size_t)(m0 + srow) * CDIM + skq;
  const f16* Bg = o16 + (size_t)(n0 + w * 64 + srow) * CDIM + skq;
  f16* lA = Asm + w * 32 * 32;
  f16* lB = Bsm + w * 64 * 32;
  // A tile is 128 rows staged by 4 waves: wave w stages rows [w*32, w*32+32)
  const f16* Agw = Ag + (size_t)(w * 32) * CDIM;

  const int rsw = (l15 >> 1) & 3;
  const int kchunk = (l4 ^ rsw) * 8;

  f32x4_t acc[4][8];
#pragma unroll
  for (int i = 0; i < 4; i++)
#pragma unroll
    for (int j = 0; j < 8; j++) acc[i][j] = (f32x4_t){0.f, 0.f, 0.f, 0.f};

  for (int k0 = 0; k0 < CDIM; k0 += 32) {
    gld_lds16(Agw + k0, lA);
    gld_lds16(Agw + 16 * CDIM + k0, lA + 16 * 32);
    gld_lds16(Bg + k0, lB);
    gld_lds16(Bg + 16 * CDIM + k0, lB + 16 * 32);
    gld_lds16(Bg + 32 * CDIM + k0, lB + 32 * 32);
    gld_lds16(Bg + 48 * CDIM + k0, lB + 48 * 32);
    __syncthreads();
    f16x8_t af[4];
#pragma unroll
    for (int mi = 0; mi < 4; mi++)
      af[mi] = *(const f16x8_t*)(Asm + (wr * 64 + mi * 16 + l15) * 32 + kchunk);
#pragma unroll
    for (int ni = 0; ni < 8; ni++) {
      f16x8_t bfv =
          *(const f16x8_t*)(Bsm + (wc * 128 + ni * 16 + l15) * 32 + kchunk);
#pragma unroll
      for (int mi = 0; mi < 4; mi++)
        acc[mi][ni] = __builtin_amdgcn_mfma_f32_16x16x32_f16(
            af[mi], bfv, acc[mi][ni], 0, 0, 0);
    }
    __syncthreads();
  }

#pragma unroll
  for (int ni = 0; ni < 8; ni++) {
    const int tok = n0 + wc * 128 + ni * 16 + l15;
    if (tok < MTOK) {
      const int bb = tok / NQTOK;
      const int nn = tok % NQTOK;
#pragma unroll
      for (int mi = 0; mi < 4; mi++) {
        const int mbase = m0 + wr * 64 + mi * 16 + l4 * 4;
#pragma unroll
        for (int r = 0; r < 4; r++) {
          float v = acc[mi][ni][r] + bias[mbase + r];
          if (nn == 0)
            cls_o[bb * CDIM + mbase + r] = v;
          else
            xo[((size_t)bb * CDIM + mbase + r) * (size_t)NSP + nn - 1] = v;
        }
      }
    }
  }
}

// ---------------------------------------------------------------------------
// Depthwise 3x3x3 conv, f16 in (row stride istride) / f16 out.
// ---------------------------------------------------------------------------
__global__ __launch_bounds__(256) void dwconv_kernel(
    const f16* __restrict__ X, const float* __restrict__ wconv,
    f16* __restrict__ Out, int Lo, int Ho, int Wo, int sh, int sw,
    int istride) {
  __shared__ float xin[NSP];
  __shared__ float wsm[27];
  const int c = blockIdx.x % CDIM;
  const int b = blockIdx.x / CDIM;
  const f16* xb = X + ((size_t)b * CDIM + c) * (size_t)istride;
  for (int i = threadIdx.x * 8; i < NSP; i += 2048) {
    f16x8_t v = *(const f16x8_t*)&xb[i];
#pragma unroll
    for (int j = 0; j < 8; j++) xin[i + j] = (float)v[j];
  }
  if (threadIdx.x < 27) wsm[threadIdx.x] = wconv[c * 27 + threadIdx.x];
  __syncthreads();
  const int npos = Lo * Ho * Wo;
  f16* ob = Out + ((size_t)b * CDIM + c) * (size_t)npos;
  for (int pos = threadIdx.x; pos < npos; pos += 256) {
    int wo = pos % Wo;
    int ho = (pos / Wo) % Ho;
    int lo = pos / (Wo * Ho);
    int li0 = lo - 1, hi0 = ho * sh - 1, wi0 = wo * sw - 1;
    float sum = 0.f;
#pragma unroll
    for (int kd = 0; kd < 3; kd++) {
      int li = li0 + kd;
      if (li < 0 || li >= LDEPTH) continue;
#pragma unroll
      for (int kh = 0; kh < 3; kh++) {
        int hi = hi0 + kh;
        if (hi < 0 || hi >= HHEIGHT) continue;
#pragma unroll
        for (int kw = 0; kw < 3; kw++) {
          int wi = wi0 + kw;
          if (wi < 0 || wi >= WWIDTH) continue;
          sum = fmaf(xin[(li * HHEIGHT + hi) * WWIDTH + wi],
                     wsm[(kd * 3 + kh) * 3 + kw], sum);
        }
      }
    }
    ob[pos] = (f16)sum;
  }
}

// ---------------------------------------------------------------------------
// Fused LayerNorm + head-pack for q/k, single-global-read version:
// phase 1 caches the raw 32-pos x 768-c tile in LDS (f16, XOR-swizzled
// slots) while accumulating stats; phase 2 normalizes from LDS and writes
// OutH. 2 barriers total.
// ---------------------------------------------------------------------------
__global__ __launch_bounds__(256) void ln_pack_qk_kernel(
    const f16* __restrict__ xp, const float* __restrict__ ln_w,
    const float* __restrict__ ln_b, f16* __restrict__ OutH, int np, int tp) {
  const int b = blockIdx.y;
  const int p0 = blockIdx.x * 32;
  const int tid = threadIdx.x;
  const int pl = tid & 31;
  const int grp = tid >> 5;
  const int pos = p0 + pl;
  const bool act = pos < np;
  const f16* Xb = xp + (size_t)b * CDIM * (size_t)np;

  __shared__ __align__(16) f16 tile[32][784];
  __shared__ float r1[8][33], r2[8][33];
  __shared__ float smean[32], srstd[32];

  const int swz = (pl & 7) << 3;
  float s1 = 0.f, s2 = 0.f;
  for (int cc = 0; cc < 12; cc++) {
    const int c0 = grp * 96 + cc * 8;
    f16x8_t hv;
#pragma unroll
    for (int i = 0; i < 8; i++) {
      f16 h = act ? Xb[(size_t)(c0 + i) * np + pos] : (f16)0.f;
      hv[i] = h;
      float v = (float)h;
      s1 += v;
      s2 = fmaf(v, v, s2);
    }
    *(f16x8_t*)&tile[pl][c0 ^ swz] = hv;
  }
  r1[grp][pl] = s1;
  r2[grp][pl] = s2;
  __syncthreads();
  if (tid < 32) {
    float t1 = 0.f, t2 = 0.f;
#pragma unroll
    for (int g = 0; g < 8; g++) { t1 += r1[g][tid]; t2 += r2[g][tid]; }
    float mean = t1 * (1.f / 768.f);
    float var = t2 * (1.f / 768.f) - mean * mean;
    smean[tid] = mean;
    srstd[tid] = rsqrtf(var + LN_EPS);
  }
  __syncthreads();

  const int tl = tid >> 3, d8 = (tid & 7) * 8;
  const float mean = smean[tl], rstd = srstd[tl];
  const bool wv = (p0 + tl) < np;
  const int tswz = (tl & 7) << 3;
#pragma unroll
  for (int h = 0; h < NHEADS; h++) {
    const int c = h * 64 + d8;
    f16x8_t raw = *(const f16x8_t*)&tile[tl][c ^ tswz];
    float4 w1 = *(const float4*)&ln_w[c];
    float4 w2 = *(const float4*)&ln_w[c + 4];
    float4 b1 = *(const float4*)&ln_b[c];
    float4 b2 = *(const float4*)&ln_b[c + 4];
    f16x8_t ov;
    ov[0] = (f16)(((float)raw[0] - mean) * rstd * w1.x + b1.x);
    ov[1] = (f16)(((float)raw[1] - mean) * rstd * w1.y + b1.y);
    ov[2] = (f16)(((float)raw[2] - mean) * rstd * w1.z + b1.z);
    ov[3] = (f16)(((float)raw[3] - mean) * rstd * w1.w + b1.w);
    ov[4] = (f16)(((float)raw[4] - mean) * rstd * w2.x + b2.x);
    ov[5] = (f16)(((float)raw[5] - mean) * rstd * w2.y + b2.y);
    ov[6] = (f16)(((float)raw[6] - mean) * rstd * w2.z + b2.z);
    ov[7] = (f16)(((float)raw[7] - mean) * rstd * w2.w + b2.w);
    if (wv)
      *(uint4*)(OutH +
                (((size_t)(b * NHEADS + h)) * (size_t)tp + (p0 + tl + 1)) * 64 +
                d8) = *(uint4*)&ov;
  }
}

// ---------------------------------------------------------------------------
// Fused LayerNorm + transpose-pack for v. cls (t=0) read raw (no LN) from
// v_lin column NSP; t in [1,392] = LN'd; t >= 393 = 0.
// ---------------------------------------------------------------------------
__global__ __launch_bounds__(256) void ln_pack_v_kernel(
    const f16* __restrict__ vp, const f16* __restrict__ vlin,
    const float* __restrict__ ln_w, const float* __restrict__ ln_b,
    f16* __restrict__ Vht) {
  const int b = blockIdx.y;
  const int t0 = blockIdx.x * 32;
  const int tid = threadIdx.x;
  const int pl = tid & 31;
  const int grp = tid >> 5;
  const int t = t0 + pl;
  const int pos = t - 1;
  const bool isv = (t >= 1) && (t < NKTOK);
  const f16* Vb = vp + (size_t)b * CDIM * (size_t)NKSP;

  __shared__ float r1[8][33], r2[8][33];
  __shared__ float smean[32], srstd[32];
  __shared__ __align__(16) f16 vtile[128][40];

  float s1 = 0.f, s2 = 0.f;
  if (isv) {
    for (int c = grp; c < CDIM; c += 8) {
      float v = (float)Vb[(size_t)c * NKSP + pos];
      s1 += v;
      s2 = fmaf(v, v, s2);
    }
  }
  r1[grp][pl] = s1;
  r2[grp][pl] = s2;
  __syncthreads();
  if (tid < 32) {
    float t1 = 0.f, t2 = 0.f;
#pragma unroll
    for (int g = 0; g < 8; g++) { t1 += r1[g][tid]; t2 += r2[g][tid]; }
    float mean = t1 * (1.f / 768.f);
    float var = t2 * (1.f / 768.f) - mean * mean;
    smean[tid] = mean;
    srstd[tid] = rsqrtf(var + LN_EPS);
  }
  __syncthreads();
  const float mean = smean[pl], rstd = srstd[pl];

  for (int cc = 0; cc < 6; cc++) {
#pragma unroll
    for (int i = 0; i < 16; i++) {
      int cl = grp * 16 + i;
      int c = cc * 128 + cl;
      float outv;
      if (isv)
        outv = ((float)Vb[(size_t)c * NKSP + pos] - mean) * rstd * ln_w[c] +
               ln_b[c];
      else if (t == 0)
        outv = (float)vlin[((size_t)b * CDIM + c) * NSPX + NSP];
      else
        outv = 0.f;
      vtile[cl][pl] = (f16)outv;
    }
    __syncthreads();
#pragma unroll
    for (int it = 0; it < 2; it++) {
      int idx = it * 256 + tid;
      int cl = idx >> 2, t8 = (idx & 3) * 8;
      uint4 vv = *(const uint4*)&vtile[cl][t8];
      *(uint4*)(Vht + ((size_t)b * CDIM + cc * 128 + cl) * (size_t)TKP + t0 +
                t8) = vv;
    }
    __syncthreads();
  }
}

// ---------------------------------------------------------------------------
// cls_fill: t=0 rows of Qh/Kh from the lin buffers' cls column (n = NSP).
// ---------------------------------------------------------------------------
__global__ __launch_bounds__(768) void cls_fill_kernel(
    const f16* __restrict__ qlin, const f16* __restrict__ klin,
    f16* __restrict__ Qh, f16* __restrict__ Kh) {
  const int b = blockIdx.x;
  const int c = threadIdx.x;
  Qh[(((size_t)(b * NHEADS + (c >> 6))) * TQP) * 64 + (c & 63)] =
      qlin[((size_t)b * CDIM + c) * NSPX + NSP];
  Kh[(((size_t)(b * NHEADS + (c >> 6))) * TKP) * 64 + (c & 63)] =
      klin[((size_t)b * CDIM + c) * NSPX + NSP];
}

// ---------------------------------------------------------------------------
// MFMA flash attention. Grid (13, 12, 8), 256 threads = 4 waves.
// ---------------------------------------------------------------------------
__global__ __launch_bounds__(256) void attn_mfma_kernel(
    const f16* __restrict__ Qh, const f16* __restrict__ Kh,
    const f16* __restrict__ Vht, f16* __restrict__ o16) {
  __shared__ __align__(16) f16 Ks[64 * 72];   // [key][d], pad 8
  __shared__ __align__(16) f16 Vt[64 * 72];   // [d][key], pad 8
  const int qt = blockIdx.x, h = blockIdx.y, b = blockIdx.z;
  const int tid = threadIdx.x;
  const int lane = tid & 63;
  const int w = tid >> 6;
  const int l15 = lane & 15, l4 = lane >> 4;
  const int q0 = qt * 128 + w * 32;

  const f16* Qp = Qh + ((size_t)(b * NHEADS + h) * TQP) * 64;
  const f16* Kp = Kh + ((size_t)(b * NHEADS + h) * TKP) * 64;
  const f16* Vp = Vht + ((size_t)(b * NHEADS + h) * 64) * TKP;

  f16x8_t bq[2][2];
#pragma unroll
  for (int qi = 0; qi < 2; qi++)
#pragma unroll
    for (int kf = 0; kf < 2; kf++)
      bq[qi][kf] = *(const f16x8_t*)(Qp + (size_t)(q0 + qi * 16 + l15) * 64 +
                                     kf * 32 + l4 * 8);

  f32x4_t oacc[4][2];
#pragma unroll
  for (int df = 0; df < 4; df++)
#pragma unroll
    for (int qi = 0; qi < 2; qi++) oacc[df][qi] = (f32x4_t){0.f, 0.f, 0.f, 0.f};
  float mrow[2] = {-1e30f, -1e30f};
  float lrow[2] = {0.f, 0.f};

  const int sr = tid >> 2, sc = (tid & 3) * 16;

  for (int kv0 = 0; kv0 < TKP; kv0 += 64) {
    const f16* kg = Kp + (size_t)(kv0 + sr) * 64 + sc;
    uint4 kl0 = *(const uint4*)kg;
    uint4 kl1 = *(const uint4*)(kg + 8);
    const f16* vg = Vp + (size_t)sr * TKP + kv0 + sc;
    uint4 vl0 = *(const uint4*)vg;
    uint4 vl1 = *(const uint4*)(vg + 8);
    __syncthreads();
    *(uint4*)(Ks + sr * 72 + sc) = kl0;
    *(uint4*)(Ks + sr * 72 + sc + 8) = kl1;
    *(uint4*)(Vt + sr * 72 + sc) = vl0;
    *(uint4*)(Vt + sr * 72 + sc + 8) = vl1;
    __syncthreads();

    f32x4_t sacc[4][2];
#pragma unroll
    for (int ki = 0; ki < 4; ki++)
#pragma unroll
      for (int qi = 0; qi < 2; qi++) sacc[ki][qi] = (f32x4_t){0.f, 0.f, 0.f, 0.f};
#pragma unroll
    for (int kf = 0; kf < 2; kf++) {
#pragma unroll
      for (int ki = 0; ki < 4; ki++) {
        f16x8_t ak =
            *(const f16x8_t*)(Ks + (ki * 16 + l15) * 72 + kf * 32 + l4 * 8);
#pragma unroll
        for (int qi = 0; qi < 2; qi++)
          sacc[ki][qi] = __builtin_amdgcn_mfma_f32_16x16x32_f16(
              ak, bq[qi][kf], sacc[ki][qi], 0, 0, 0);
      }
    }

    float pmax[2] = {-1e30f, -1e30f};
#pragma unroll
    for (int ki = 0; ki < 4; ki++) {
      const int keyb = kv0 + ki * 16 + l4 * 4;
#pragma unroll
      for (int qi = 0; qi < 2; qi++) {
#pragma unroll
        for (int rr = 0; rr < 4; rr++) {
          float s = sacc[ki][qi][rr] * ATTN_SCALE;
          if (keyb + rr >= NKTOK) s = -1e30f;
          sacc[ki][qi][rr] = s;
          pmax[qi] = fmaxf(pmax[qi], s);
        }
      }
    }
#pragma unroll
    for (int qi = 0; qi < 2; qi++) {
      pmax[qi] = fmaxf(pmax[qi], __shfl_xor(pmax[qi], 16, 64));
      pmax[qi] = fmaxf(pmax[qi], __shfl_xor(pmax[qi], 32, 64));
      float mnew = fmaxf(mrow[qi], pmax[qi]);
      float alpha = __expf(mrow[qi] - mnew);
      mrow[qi] = mnew;
      lrow[qi] *= alpha;
#pragma unroll
      for (int df = 0; df < 4; df++) {
        oacc[df][qi][0] *= alpha;
        oacc[df][qi][1] *= alpha;
        oacc[df][qi][2] *= alpha;
        oacc[df][qi][3] *= alpha;
      }
    }
    f16x4_t pb[4][2];
#pragma unroll
    for (int ki = 0; ki < 4; ki++) {
#pragma unroll
      for (int qi = 0; qi < 2; qi++) {
        float p0 = __expf(sacc[ki][qi][0] - mrow[qi]);
        float p1 = __expf(sacc[ki][qi][1] - mrow[qi]);
        float p2 = __expf(sacc[ki][qi][2] - mrow[qi]);
        float p3 = __expf(sacc[ki][qi][3] - mrow[qi]);
        lrow[qi] += p0 + p1 + p2 + p3;
        f16x4_t pv = {(f16)p0, (f16)p1, (f16)p2, (f16)p3};
        pb[ki][qi] = pv;
      }
    }

#pragma unroll
    for (int df = 0; df < 4; df++) {
#pragma unroll
      for (int ki = 0; ki < 4; ki++) {
        f16x4_t av =
            *(const f16x4_t*)(Vt + (df * 16 + l15) * 72 + ki * 16 + l4 * 4);
#pragma unroll
        for (int qi = 0; qi < 2; qi++)
          oacc[df][qi] = __builtin_amdgcn_mfma_f32_16x16x16f16(
              av, pb[ki][qi], oacc[df][qi], 0, 0, 0);
      }
    }
  }

  float inv[2];
#pragma unroll
  for (int qi = 0; qi < 2; qi++) {
    float l = lrow[qi];
    l += __shfl_xor(l, 16, 64);
    l += __shfl_xor(l, 32, 64);
    inv[qi] = 1.f / l;
  }
#pragma unroll
  for (int qi = 0; qi < 2; qi++) {
    const int q = q0 + qi * 16 + l15;
    if (q < NQTOK) {
      f16* op = o16 + ((size_t)(b * NQTOK + q)) * CDIM + h * 64 + l4 * 4;
#pragma unroll
      for (int df = 0; df < 4; df++) {
        f16x4_t ov = {(f16)(oacc[df][qi][0] * inv[qi]),
                      (f16)(oacc[df][qi][1] * inv[qi]),
                      (f16)(oacc[df][qi][2] * inv[qi]),
                      (f16)(oacc[df][qi][3] * inv[qi])};
        *(f16x4_t*)(op + df * 16) = ov;
      }
    }
  }
}

// ---------------------------------------------------------------------------
extern "C" void kernel_launch(void* const* d_in, const int* in_sizes, int n_in,
                              void* d_out, int out_size, void* d_ws, size_t ws_size,
                              hipStream_t stream) {
  const float* x      = (const float*)d_in[0];
  const float* cls    = (const float*)d_in[1];
  const float* Wq     = (const float*)d_in[2];
  const float* bq     = (const float*)d_in[3];
  const float* Wk     = (const float*)d_in[4];
  const float* bk     = (const float*)d_in[5];
  const float* Wv     = (const float*)d_in[6];
  const float* bv     = (const float*)d_in[7];
  const float* conv_q = (const float*)d_in[8];
  const float* conv_k = (const float*)d_in[9];
  const float* conv_v = (const float*)d_in[10];
  const float* lnq_w  = (const float*)d_in[11];
  const float* lnq_b  = (const float*)d_in[12];
  const float* lnk_w  = (const float*)d_in[13];
  const float* lnk_b  = (const float*)d_in[14];
  const float* lnv_w  = (const float*)d_in[15];
  const float* lnv_b  = (const float*)d_in[16];
  const float* Wproj  = (const float*)d_in[17];
  const float* bproj  = (const float*)d_in[18];

  // Workspace layout (bytes). Total = 105,480,192 B ≈ 105.5 MB.
  char* wsb = (char*)d_ws;
  f16*   Xt     = (f16*)(wsb + 0);           // 8*1792*768*2 = 22,020,096
  f16*   W16    = (f16*)(wsb + 22020096);    //  4,718,592
  f16*   q_lin  = (f16*)(wsb + 26738688);    // 8*768*1576*2 = 19,365,888
  f16*   k_lin  = (f16*)(wsb + 46104576);    // 19,365,888
  f16*   v_lin  = (f16*)(wsb + 65470464);    // 19,365,888
  f16*   k_pool = (f16*)(wsb + 84836352);    //  4,816,896
  f16*   v_pool = (f16*)(wsb + 89653248);    //  4,816,896
  f16*   Kh     = (f16*)(wsb + 94470144);    //  5,505,024
  f16*   Vht    = (f16*)(wsb + 99975168);    //  5,505,024 -> end 105,480,192
  f16*   q_pool = k_lin;   // alias: k_lin dead after dwconv_k + cls_fill
  f16*   Qh     = Xt;      // alias: Xt dead after QKV GEMM (20.4 <= 22.0 MB)
  f16*   o16    = v_lin;   // alias: v_lin (+294KB of dead k_pool) at proj;
                           // attn writes only rows < 12552 (within v_lin)

  f16* W16p = W16 + (size_t)3 * WELEM;

  // 1. convert weights to fp16
  convert4_kernel<<<dim3(576, 4), 256, 0, stream>>>(Wq, Wk, Wv, Wproj, W16);

  // 2. transpose+convert X (+cls as row 1568) -> Xt
  transpose_x_kernel<<<dim3(56, 24, BATCH), 256, 0, stream>>>(x, cls, Xt);

  // 3. fused QKV MFMA GEMM (128x256 tile) -> f16 lin buffers (stride 1576,
  //    col 1568 = cls outputs)
  gemm_qkv_f16_kernel<<<1008, 256, 0, stream>>>(W16, Xt, bq, bk, bv, q_lin);

  // 4. depthwise convs; cls_fill before dwconv_q (q_pool aliases k_lin)
  dwconv_kernel<<<BATCH * CDIM, 256, 0, stream>>>(k_lin, conv_k, k_pool,
                                                  8, 7, 7, 2, 2, NSPX);
  dwconv_kernel<<<BATCH * CDIM, 256, 0, stream>>>(v_lin, conv_v, v_pool,
                                                  8, 7, 7, 2, 2, NSPX);
  cls_fill_kernel<<<BATCH, 768, 0, stream>>>(q_lin, k_lin, Qh, Kh);
  dwconv_kernel<<<BATCH * CDIM, 256, 0, stream>>>(q_lin, conv_q, q_pool,
                                                  8, 14, 14, 1, 1, NSPX);

  // 5. fused LN + pack
  ln_pack_qk_kernel<<<dim3(49, BATCH), 256, 0, stream>>>(q_pool, lnq_w, lnq_b,
                                                         Qh, NSP, TQP);
  ln_pack_qk_kernel<<<dim3(13, BATCH), 256, 0, stream>>>(k_pool, lnk_w, lnk_b,
                                                         Kh, NKSP, TKP);
  ln_pack_v_kernel<<<dim3(14, BATCH), 256, 0, stream>>>(v_pool, v_lin, lnv_w,
                                                        lnv_b, Vht);

  // 6. MFMA attention -> o16
  attn_mfma_kernel<<<dim3(13, NHEADS, BATCH), 256, 0, stream>>>(Qh, Kh, Vht,
                                                                o16);

  // 7. projection MFMA GEMM (128x256, bijective XCD swizzle) -> d_out
  float* xo = (float*)d_out;
  float* cls_o = (float*)d_out + (size_t)BATCH * CDIM * NSP;
  gemm_proj_f16_kernel<<<300, 256, 0, stream>>>(W16p, o16, bproj, xo, cls_o);
}

// Round 10
// 352.893 us; speedup vs baseline: 1.3902x; 1.0086x over previous
//
#include <hip/hip_runtime.h>

#define CDIM 768
#define BATCH 8
#define LDEPTH 8
#define HHEIGHT 14
#define WWIDTH 14
#define NSP 1568      // 8*14*14 spatial tokens (input / q)
#define NSPX 1576     // lin-buffer row stride: NSP + cls col (1568) + pad
#define NQTOK 1569    // +cls
#define NKSP 392      // 8*7*7 spatial tokens (k/v after pool)
#define NKTOK 393
#define NHEADS 12
#define HEADDIM 64
#define ATTN_SCALE 0.125f
#define LN_EPS 1e-6f
#define MTOK (BATCH * NQTOK)   // 12552 tokens for proj GEMM
#define NPAD_X 1792            // Xt padded rows per batch (7 tiles * 256)
#define WELEM (CDIM * CDIM)    // 589824
#define TQP 1792               // padded q tokens per (b,h)  (7*256)
#define TKP 448                // padded kv tokens per (b,h) (7*64)

typedef _Float16 f16;
typedef _Float16 f16x8_t __attribute__((ext_vector_type(8)));
typedef _Float16 f16x4_t __attribute__((ext_vector_type(4)));
typedef float f32x4_t __attribute__((ext_vector_type(4)));

// global -> LDS direct 16B copy (wave-uniform LDS base + lane*16)
__device__ __forceinline__ void gld_lds16(const void* g, void* l) {
  __builtin_amdgcn_global_load_lds(
      (const __attribute__((address_space(1))) void*)g,
      (__attribute__((address_space(3))) void*)l, 16, 0, 0);
}

// ---------------------------------------------------------------------------
// fp32 -> fp16 convert for the 4 weight matrices (one launch, grid.y = mat)
// ---------------------------------------------------------------------------
__global__ __launch_bounds__(256) void convert4_kernel(
    const float* __restrict__ s0, const float* __restrict__ s1,
    const float* __restrict__ s2, const float* __restrict__ s3,
    f16* __restrict__ dst) {
  const int mat = blockIdx.y;
  const float* src = (mat == 0) ? s0 : (mat == 1) ? s1 : (mat == 2) ? s2 : s3;
  int i = (blockIdx.x * 256 + threadIdx.x) * 4;
  if (i < WELEM) {
    float4 v = *(const float4*)&src[i];
    f16x4_t h = {(f16)v.x, (f16)v.y, (f16)v.z, (f16)v.w};
    *(f16x4_t*)&dst[(size_t)mat * WELEM + i] = h;
  }
}

// ---------------------------------------------------------------------------
// Transpose+convert X: (B,768,1568) f32 -> Xt (B,1792,768) f16.
// Row 1568 = class_token; rows >1568 = 0.
// ---------------------------------------------------------------------------
__global__ __launch_bounds__(256) void transpose_x_kernel(
    const float* __restrict__ X, const float* __restrict__ cls,
    f16* __restrict__ Xt) {
  __shared__ float t[32][33];
  const int b = blockIdx.z;
  const int k0 = blockIdx.y * 32;
  const int n0 = blockIdx.x * 32;   // grid.x = 56 (1792/32)
  const int tx = threadIdx.x & 31, ty = threadIdx.x >> 5;
#pragma unroll
  for (int i = 0; i < 4; i++) {
    int k = k0 + ty + i * 8;
    int n = n0 + tx;
    float v;
    if (n < NSP)
      v = X[((size_t)b * CDIM + k) * NSP + n];
    else if (n == NSP)
      v = cls[b * CDIM + k];
    else
      v = 0.f;
    t[ty + i * 8][tx] = v;
  }
  __syncthreads();
#pragma unroll
  for (int i = 0; i < 4; i++) {
    int n = n0 + ty + i * 8;
    Xt[((size_t)b * NPAD_X + n) * CDIM + k0 + tx] = (f16)t[tx][ty + i * 8];
  }
}

// ---------------------------------------------------------------------------
// Fused QKV MFMA GEMM. Block tile 128(m) x 256(n), BK=32, 4 waves, wave tile
// 64x128 (acc[4][8]). global_load_lds staging with SOURCE-side XOR swizzle
// matched by read-side XOR. 1D grid 1008, XCD swizzle: batch = bid&7.
// ---------------------------------------------------------------------------
__global__ __launch_bounds__(256, 2) void gemm_qkv_f16_kernel(
    const f16* __restrict__ W16, const f16* __restrict__ Xt,
    const float* __restrict__ bq, const float* __restrict__ bk,
    const float* __restrict__ bv, f16* __restrict__ OutBase) {
  __shared__ __align__(16) f16 Asm[128 * 32];   // 8 KB
  __shared__ __align__(16) f16 Bsm[256 * 32];   // 16 KB

  const int bid = blockIdx.x;
  const int b = bid & 7;
  const int rem = bid >> 3;
  const int mat = rem / 42;
  const int rem2 = rem % 42;
  const int m0 = (rem2 / 7) * 128;
  const int n0 = (rem2 % 7) * 256;
  const int tid = threadIdx.x;
  const int lane = tid & 63;
  const int w = tid >> 6;
  const int wr = w >> 1, wc = w & 1;
  const int l15 = lane & 15, l4 = lane >> 4;

  const f16* A16 = W16 + (size_t)mat * WELEM;
  const float* bias = (mat == 0) ? bq : (mat == 1) ? bk : bv;
  f16* Out = OutBase + (size_t)mat * ((size_t)BATCH * CDIM * NSPX);

  const int srow = lane >> 2;
  const int skq = ((lane & 3) ^ ((lane >> 3) & 3)) * 8;
  const f16* Ag = A16 + (size_t)(m0 + w * 32 + srow) * CDIM + skq;
  const f16* Bg = Xt + ((size_t)b * NPAD_X + n0 + w * 64 + srow) * CDIM + skq;
  f16* lA = Asm + w * 32 * 32;
  f16* lB = Bsm + w * 64 * 32;

  const int rsw = (l15 >> 1) & 3;
  const int kchunk = (l4 ^ rsw) * 8;

  f32x4_t acc[4][8];
#pragma unroll
  for (int i = 0; i < 4; i++)
#pragma unroll
    for (int j = 0; j < 8; j++) acc[i][j] = (f32x4_t){0.f, 0.f, 0.f, 0.f};

  for (int k0 = 0; k0 < CDIM; k0 += 32) {
    gld_lds16(Ag + k0, lA);
    gld_lds16(Ag + 16 * CDIM + k0, lA + 16 * 32);
    gld_lds16(Bg + k0, lB);
    gld_lds16(Bg + 16 * CDIM + k0, lB + 16 * 32);
    gld_lds16(Bg + 32 * CDIM + k0, lB + 32 * 32);
    gld_lds16(Bg + 48 * CDIM + k0, lB + 48 * 32);
    __syncthreads();
    f16x8_t af[4];
#pragma unroll
    for (int mi = 0; mi < 4; mi++)
      af[mi] = *(const f16x8_t*)(Asm + (wr * 64 + mi * 16 + l15) * 32 + kchunk);
#pragma unroll
    for (int ni = 0; ni < 8; ni++) {
      f16x8_t bfv =
          *(const f16x8_t*)(Bsm + (wc * 128 + ni * 16 + l15) * 32 + kchunk);
#pragma unroll
      for (int mi = 0; mi < 4; mi++)
        acc[mi][ni] = __builtin_amdgcn_mfma_f32_16x16x32_f16(
            af[mi], bfv, acc[mi][ni], 0, 0, 0);
    }
    __syncthreads();
  }

#pragma unroll
  for (int mi = 0; mi < 4; mi++) {
    const int mbase = m0 + wr * 64 + mi * 16 + l4 * 4;
#pragma unroll
    for (int ni = 0; ni < 8; ni++) {
      const int n = n0 + wc * 128 + ni * 16 + l15;
      if (n < NQTOK) {   // n == 1568 is the cls column
#pragma unroll
        for (int r = 0; r < 4; r++) {
          Out[((size_t)b * CDIM + mbase + r) * NSPX + n] =
              (f16)(acc[mi][ni][r] + bias[mbase + r]);
        }
      }
    }
  }
}

// ---------------------------------------------------------------------------
// Projection MFMA GEMM, same 128x256 structure. 1D grid 300, bijective XCD
// swizzle (nwg=300: q=37, r=4).
// ---------------------------------------------------------------------------
__global__ __launch_bounds__(256, 2) void gemm_proj_f16_kernel(
    const f16* __restrict__ Wp16, const f16* __restrict__ o16,
    const float* __restrict__ bias, float* __restrict__ xo,
    float* __restrict__ cls_o) {
  __shared__ __align__(16) f16 Asm[128 * 32];
  __shared__ __align__(16) f16 Bsm[256 * 32];

  const int bid = blockIdx.x;
  const int xcd = bid & 7, pos_ = bid >> 3;
  const int base = (xcd < 4) ? xcd * 38 : 152 + (xcd - 4) * 37;
  const int wgid = base + pos_;
  const int m0 = (wgid / 50) * 128;
  const int n0 = (wgid % 50) * 256;
  const int tid = threadIdx.x;
  const int lane = tid & 63;
  const int w = tid >> 6;
  const int wr = w >> 1, wc = w & 1;
  const int l15 = lane & 15, l4 = lane >> 4;

  const int srow = lane >> 2;
  const int skq = ((lane & 3) ^ ((lane >> 3) & 3)) * 8;
  const f16* Ag = Wp16 + (size_t)(m0 + srow) * CDIM + skq;
  const f16* Bg = o16 + (size_t)(n0 + w * 64 + srow) * CDIM + skq;
  f16* lA = Asm + w * 32 * 32;
  f16* lB = Bsm + w * 64 * 32;
  const f16* Agw = Ag + (size_t)(w * 32) * CDIM;

  const int rsw = (l15 >> 1) & 3;
  const int kchunk = (l4 ^ rsw) * 8;

  f32x4_t acc[4][8];
#pragma unroll
  for (int i = 0; i < 4; i++)
#pragma unroll
    for (int j = 0; j < 8; j++) acc[i][j] = (f32x4_t){0.f, 0.f, 0.f, 0.f};

  for (int k0 = 0; k0 < CDIM; k0 += 32) {
    gld_lds16(Agw + k0, lA);
    gld_lds16(Agw + 16 * CDIM + k0, lA + 16 * 32);
    gld_lds16(Bg + k0, lB);
    gld_lds16(Bg + 16 * CDIM + k0, lB + 16 * 32);
    gld_lds16(Bg + 32 * CDIM + k0, lB + 32 * 32);
    gld_lds16(Bg + 48 * CDIM + k0, lB + 48 * 32);
    __syncthreads();
    f16x8_t af[4];
#pragma unroll
    for (int mi = 0; mi < 4; mi++)
      af[mi] = *(const f16x8_t*)(Asm + (wr * 64 + mi * 16 + l15) * 32 + kchunk);
#pragma unroll
    for (int ni = 0; ni < 8; ni++) {
      f16x8_t bfv =
          *(const f16x8_t*)(Bsm + (wc * 128 + ni * 16 + l15) * 32 + kchunk);
#pragma unroll
      for (int mi = 0; mi < 4; mi++)
        acc[mi][ni] = __builtin_amdgcn_mfma_f32_16x16x32_f16(
            af[mi], bfv, acc[mi][ni], 0, 0, 0);
    }
    __syncthreads();
  }

#pragma unroll
  for (int ni = 0; ni < 8; ni++) {
    const int tok = n0 + wc * 128 + ni * 16 + l15;
    if (tok < MTOK) {
      const int bb = tok / NQTOK;
      const int nn = tok % NQTOK;
#pragma unroll
      for (int mi = 0; mi < 4; mi++) {
        const int mbase = m0 + wr * 64 + mi * 16 + l4 * 4;
#pragma unroll
        for (int r = 0; r < 4; r++) {
          float v = acc[mi][ni][r] + bias[mbase + r];
          if (nn == 0)
            cls_o[bb * CDIM + mbase + r] = v;
          else
            xo[((size_t)bb * CDIM + mbase + r) * (size_t)NSP + nn - 1] = v;
        }
      }
    }
  }
}

// ---------------------------------------------------------------------------
// Fused depthwise 3x3x3 convs: grid (B*CDIM, 3). y=0: k, y=1: v, y=2: q.
// f16 in (row stride NSPX) / f16 out (f32 accumulate).
// ---------------------------------------------------------------------------
__global__ __launch_bounds__(256) void dwconv3_kernel(
    const f16* __restrict__ q_lin, const f16* __restrict__ k_lin,
    const f16* __restrict__ v_lin, const float* __restrict__ cq,
    const float* __restrict__ ck, const float* __restrict__ cv,
    f16* __restrict__ q_pool, f16* __restrict__ k_pool,
    f16* __restrict__ v_pool) {
  __shared__ float xin[NSP];
  __shared__ float wsm[27];
  const int which = blockIdx.y;
  const f16* X = (which == 0) ? k_lin : (which == 1) ? v_lin : q_lin;
  const float* wconv = (which == 0) ? ck : (which == 1) ? cv : cq;
  f16* Out = (which == 0) ? k_pool : (which == 1) ? v_pool : q_pool;
  const int Ho = (which == 2) ? 14 : 7;
  const int s = (which == 2) ? 1 : 2;
  const int c = blockIdx.x % CDIM;
  const int b = blockIdx.x / CDIM;
  const f16* xb = X + ((size_t)b * CDIM + c) * (size_t)NSPX;
  for (int i = threadIdx.x * 8; i < NSP; i += 2048) {
    f16x8_t v = *(const f16x8_t*)&xb[i];
#pragma unroll
    for (int j = 0; j < 8; j++) xin[i + j] = (float)v[j];
  }
  if (threadIdx.x < 27) wsm[threadIdx.x] = wconv[c * 27 + threadIdx.x];
  __syncthreads();
  const int npos = 8 * Ho * Ho;
  f16* ob = Out + ((size_t)b * CDIM + c) * (size_t)npos;
  for (int pos = threadIdx.x; pos < npos; pos += 256) {
    int wo = pos % Ho;
    int ho = (pos / Ho) % Ho;
    int lo = pos / (Ho * Ho);
    int li0 = lo - 1, hi0 = ho * s - 1, wi0 = wo * s - 1;
    float sum = 0.f;
#pragma unroll
    for (int kd = 0; kd < 3; kd++) {
      int li = li0 + kd;
      if (li < 0 || li >= LDEPTH) continue;
#pragma unroll
      for (int kh = 0; kh < 3; kh++) {
        int hi = hi0 + kh;
        if (hi < 0 || hi >= HHEIGHT) continue;
#pragma unroll
        for (int kw = 0; kw < 3; kw++) {
          int wi = wi0 + kw;
          if (wi < 0 || wi >= WWIDTH) continue;
          sum = fmaf(xin[(li * HHEIGHT + hi) * WWIDTH + wi],
                     wsm[(kd * 3 + kh) * 3 + kw], sum);
        }
      }
    }
    ob[pos] = (f16)sum;
  }
}

// ---------------------------------------------------------------------------
// Fused LayerNorm + head-pack for q AND k in one launch: grid (62, B);
// blockIdx.x < 49 -> q tile, else k tile. Single global read into LDS-cached
// raw tile (XOR-swizzled), 2 barriers.
// ---------------------------------------------------------------------------
__global__ __launch_bounds__(256) void ln_pack_qk2_kernel(
    const f16* __restrict__ qp, const f16* __restrict__ kp,
    const float* __restrict__ lnq_w, const float* __restrict__ lnq_b,
    const float* __restrict__ lnk_w, const float* __restrict__ lnk_b,
    f16* __restrict__ Qh, f16* __restrict__ Kh) {
  const int bx = blockIdx.x;
  const bool isq = bx < 49;
  const f16* xp = isq ? qp : kp;
  const float* ln_w = isq ? lnq_w : lnk_w;
  const float* ln_b = isq ? lnq_b : lnk_b;
  f16* OutH = isq ? Qh : Kh;
  const int np = isq ? NSP : NKSP;
  const int tp = isq ? TQP : TKP;
  const int b = blockIdx.y;
  const int p0 = (isq ? bx : bx - 49) * 32;
  const int tid = threadIdx.x;
  const int pl = tid & 31;
  const int grp = tid >> 5;
  const int pos = p0 + pl;
  const bool act = pos < np;
  const f16* Xb = xp + (size_t)b * CDIM * (size_t)np;

  __shared__ __align__(16) f16 tile[32][784];
  __shared__ float r1[8][33], r2[8][33];
  __shared__ float smean[32], srstd[32];

  const int swz = (pl & 7) << 3;
  float s1 = 0.f, s2 = 0.f;
  for (int cc = 0; cc < 12; cc++) {
    const int c0 = grp * 96 + cc * 8;
    f16x8_t hv;
#pragma unroll
    for (int i = 0; i < 8; i++) {
      f16 h = act ? Xb[(size_t)(c0 + i) * np + pos] : (f16)0.f;
      hv[i] = h;
      float v = (float)h;
      s1 += v;
      s2 = fmaf(v, v, s2);
    }
    *(f16x8_t*)&tile[pl][c0 ^ swz] = hv;
  }
  r1[grp][pl] = s1;
  r2[grp][pl] = s2;
  __syncthreads();
  if (tid < 32) {
    float t1 = 0.f, t2 = 0.f;
#pragma unroll
    for (int g = 0; g < 8; g++) { t1 += r1[g][tid]; t2 += r2[g][tid]; }
    float mean = t1 * (1.f / 768.f);
    float var = t2 * (1.f / 768.f) - mean * mean;
    smean[tid] = mean;
    srstd[tid] = rsqrtf(var + LN_EPS);
  }
  __syncthreads();

  const int tl = tid >> 3, d8 = (tid & 7) * 8;
  const float mean = smean[tl], rstd = srstd[tl];
  const bool wv = (p0 + tl) < np;
  const int tswz = (tl & 7) << 3;
#pragma unroll
  for (int h = 0; h < NHEADS; h++) {
    const int c = h * 64 + d8;
    f16x8_t raw = *(const f16x8_t*)&tile[tl][c ^ tswz];
    float4 w1 = *(const float4*)&ln_w[c];
    float4 w2 = *(const float4*)&ln_w[c + 4];
    float4 b1 = *(const float4*)&ln_b[c];
    float4 b2 = *(const float4*)&ln_b[c + 4];
    f16x8_t ov;
    ov[0] = (f16)(((float)raw[0] - mean) * rstd * w1.x + b1.x);
    ov[1] = (f16)(((float)raw[1] - mean) * rstd * w1.y + b1.y);
    ov[2] = (f16)(((float)raw[2] - mean) * rstd * w1.z + b1.z);
    ov[3] = (f16)(((float)raw[3] - mean) * rstd * w1.w + b1.w);
    ov[4] = (f16)(((float)raw[4] - mean) * rstd * w2.x + b2.x);
    ov[5] = (f16)(((float)raw[5] - mean) * rstd * w2.y + b2.y);
    ov[6] = (f16)(((float)raw[6] - mean) * rstd * w2.z + b2.z);
    ov[7] = (f16)(((float)raw[7] - mean) * rstd * w2.w + b2.w);
    if (wv)
      *(uint4*)(OutH +
                (((size_t)(b * NHEADS + h)) * (size_t)tp + (p0 + tl + 1)) * 64 +
                d8) = *(uint4*)&ov;
  }
}

// ---------------------------------------------------------------------------
// Fused LayerNorm + transpose-pack for v. cls (t=0) raw from v_lin col NSP.
// ---------------------------------------------------------------------------
__global__ __launch_bounds__(256) void ln_pack_v_kernel(
    const f16* __restrict__ vp, const f16* __restrict__ vlin,
    const float* __restrict__ ln_w, const float* __restrict__ ln_b,
    f16* __restrict__ Vht) {
  const int b = blockIdx.y;
  const int t0 = blockIdx.x * 32;
  const int tid = threadIdx.x;
  const int pl = tid & 31;
  const int grp = tid >> 5;
  const int t = t0 + pl;
  const int pos = t - 1;
  const bool isv = (t >= 1) && (t < NKTOK);
  const f16* Vb = vp + (size_t)b * CDIM * (size_t)NKSP;

  __shared__ float r1[8][33], r2[8][33];
  __shared__ float smean[32], srstd[32];
  __shared__ __align__(16) f16 vtile[128][40];

  float s1 = 0.f, s2 = 0.f;
  if (isv) {
    for (int c = grp; c < CDIM; c += 8) {
      float v = (float)Vb[(size_t)c * NKSP + pos];
      s1 += v;
      s2 = fmaf(v, v, s2);
    }
  }
  r1[grp][pl] = s1;
  r2[grp][pl] = s2;
  __syncthreads();
  if (tid < 32) {
    float t1 = 0.f, t2 = 0.f;
#pragma unroll
    for (int g = 0; g < 8; g++) { t1 += r1[g][tid]; t2 += r2[g][tid]; }
    float mean = t1 * (1.f / 768.f);
    float var = t2 * (1.f / 768.f) - mean * mean;
    smean[tid] = mean;
    srstd[tid] = rsqrtf(var + LN_EPS);
  }
  __syncthreads();
  const float mean = smean[pl], rstd = srstd[pl];

  for (int cc = 0; cc < 6; cc++) {
#pragma unroll
    for (int i = 0; i < 16; i++) {
      int cl = grp * 16 + i;
      int c = cc * 128 + cl;
      float outv;
      if (isv)
        outv = ((float)Vb[(size_t)c * NKSP + pos] - mean) * rstd * ln_w[c] +
               ln_b[c];
      else if (t == 0)
        outv = (float)vlin[((size_t)b * CDIM + c) * NSPX + NSP];
      else
        outv = 0.f;
      vtile[cl][pl] = (f16)outv;
    }
    __syncthreads();
#pragma unroll
    for (int it = 0; it < 2; it++) {
      int idx = it * 256 + tid;
      int cl = idx >> 2, t8 = (idx & 3) * 8;
      uint4 vv = *(const uint4*)&vtile[cl][t8];
      *(uint4*)(Vht + ((size_t)b * CDIM + cc * 128 + cl) * (size_t)TKP + t0 +
                t8) = vv;
    }
    __syncthreads();
  }
}

// ---------------------------------------------------------------------------
// cls_fill: t=0 rows of Qh/Kh from the lin buffers' cls column (n = NSP).
// ---------------------------------------------------------------------------
__global__ __launch_bounds__(768) void cls_fill_kernel(
    const f16* __restrict__ qlin, const f16* __restrict__ klin,
    f16* __restrict__ Qh, f16* __restrict__ Kh) {
  const int b = blockIdx.x;
  const int c = threadIdx.x;
  Qh[(((size_t)(b * NHEADS + (c >> 6))) * TQP) * 64 + (c & 63)] =
      qlin[((size_t)b * CDIM + c) * NSPX + NSP];
  Kh[(((size_t)(b * NHEADS + (c >> 6))) * TKP) * 64 + (c & 63)] =
      klin[((size_t)b * CDIM + c) * NSPX + NSP];
}

// ---------------------------------------------------------------------------
// MFMA flash attention. Grid (7, 12, 8), 256 threads = 4 waves; wave tile
// 64 q x 64 keys (bq[4][2], sacc[4][4], oacc[4][4]) -> 2x arithmetic
// intensity on LDS reads and half the K/V staging vs 32-q waves.
// ---------------------------------------------------------------------------
__global__ __launch_bounds__(256) void attn_mfma_kernel(
    const f16* __restrict__ Qh, const f16* __restrict__ Kh,
    const f16* __restrict__ Vht, f16* __restrict__ o16) {
  __shared__ __align__(16) f16 Ks[64 * 72];   // [key][d], pad 8
  __shared__ __align__(16) f16 Vt[64 * 72];   // [d][key], pad 8
  const int qt = blockIdx.x, h = blockIdx.y, b = blockIdx.z;
  const int tid = threadIdx.x;
  const int lane = tid & 63;
  const int w = tid >> 6;
  const int l15 = lane & 15, l4 = lane >> 4;
  const int q0 = qt * 256 + w * 64;

  const f16* Qp = Qh + ((size_t)(b * NHEADS + h) * TQP) * 64;
  const f16* Kp = Kh + ((size_t)(b * NHEADS + h) * TKP) * 64;
  const f16* Vp = Vht + ((size_t)(b * NHEADS + h) * 64) * TKP;

  f16x8_t bq[4][2];
#pragma unroll
  for (int qi = 0; qi < 4; qi++)
#pragma unroll
    for (int kf = 0; kf < 2; kf++)
      bq[qi][kf] = *(const f16x8_t*)(Qp + (size_t)(q0 + qi * 16 + l15) * 64 +
                                     kf * 32 + l4 * 8);

  f32x4_t oacc[4][4];
#pragma unroll
  for (int df = 0; df < 4; df++)
#pragma unroll
    for (int qi = 0; qi < 4; qi++) oacc[df][qi] = (f32x4_t){0.f, 0.f, 0.f, 0.f};
  float mrow[4] = {-1e30f, -1e30f, -1e30f, -1e30f};
  float lrow[4] = {0.f, 0.f, 0.f, 0.f};

  const int sr = tid >> 2, sc = (tid & 3) * 16;

  for (int kv0 = 0; kv0 < TKP; kv0 += 64) {
    const f16* kg = Kp + (size_t)(kv0 + sr) * 64 + sc;
    uint4 kl0 = *(const uint4*)kg;
    uint4 kl1 = *(const uint4*)(kg + 8);
    const f16* vg = Vp + (size_t)sr * TKP + kv0 + sc;
    uint4 vl0 = *(const uint4*)vg;
    uint4 vl1 = *(const uint4*)(vg + 8);
    __syncthreads();
    *(uint4*)(Ks + sr * 72 + sc) = kl0;
    *(uint4*)(Ks + sr * 72 + sc + 8) = kl1;
    *(uint4*)(Vt + sr * 72 + sc) = vl0;
    *(uint4*)(Vt + sr * 72 + sc + 8) = vl1;
    __syncthreads();

    // ---- S^T = K * Q^T ----
    f32x4_t sacc[4][4];
#pragma unroll
    for (int ki = 0; ki < 4; ki++)
#pragma unroll
      for (int qi = 0; qi < 4; qi++)
        sacc[ki][qi] = (f32x4_t){0.f, 0.f, 0.f, 0.f};
#pragma unroll
    for (int kf = 0; kf < 2; kf++) {
#pragma unroll
      for (int ki = 0; ki < 4; ki++) {
        f16x8_t ak =
            *(const f16x8_t*)(Ks + (ki * 16 + l15) * 72 + kf * 32 + l4 * 8);
#pragma unroll
        for (int qi = 0; qi < 4; qi++)
          sacc[ki][qi] = __builtin_amdgcn_mfma_f32_16x16x32_f16(
              ak, bq[qi][kf], sacc[ki][qi], 0, 0, 0);
      }
    }

    // ---- scale + mask + online softmax ----
    float pmax[4] = {-1e30f, -1e30f, -1e30f, -1e30f};
#pragma unroll
    for (int ki = 0; ki < 4; ki++) {
      const int keyb = kv0 + ki * 16 + l4 * 4;
#pragma unroll
      for (int qi = 0; qi < 4; qi++) {
#pragma unroll
        for (int rr = 0; rr < 4; rr++) {
          float s = sacc[ki][qi][rr] * ATTN_SCALE;
          if (keyb + rr >= NKTOK) s = -1e30f;
          sacc[ki][qi][rr] = s;
          pmax[qi] = fmaxf(pmax[qi], s);
        }
      }
    }
#pragma unroll
    for (int qi = 0; qi < 4; qi++) {
      pmax[qi] = fmaxf(pmax[qi], __shfl_xor(pmax[qi], 16, 64));
      pmax[qi] = fmaxf(pmax[qi], __shfl_xor(pmax[qi], 32, 64));
      float mnew = fmaxf(mrow[qi], pmax[qi]);
      float alpha = __expf(mrow[qi] - mnew);
      mrow[qi] = mnew;
      lrow[qi] *= alpha;
#pragma unroll
      for (int df = 0; df < 4; df++) {
        oacc[df][qi][0] *= alpha;
        oacc[df][qi][1] *= alpha;
        oacc[df][qi][2] *= alpha;
        oacc[df][qi][3] *= alpha;
      }
    }

    // ---- per-ki P + PV (keeps pb liveness at one ki) ----
#pragma unroll
    for (int ki = 0; ki < 4; ki++) {
      f16x4_t pb[4];
#pragma unroll
      for (int qi = 0; qi < 4; qi++) {
        float p0 = __expf(sacc[ki][qi][0] - mrow[qi]);
        float p1 = __expf(sacc[ki][qi][1] - mrow[qi]);
        float p2 = __expf(sacc[ki][qi][2] - mrow[qi]);
        float p3 = __expf(sacc[ki][qi][3] - mrow[qi]);
        lrow[qi] += p0 + p1 + p2 + p3;
        f16x4_t pv = {(f16)p0, (f16)p1, (f16)p2, (f16)p3};
        pb[qi] = pv;
      }
#pragma unroll
      for (int df = 0; df < 4; df++) {
        f16x4_t av =
            *(const f16x4_t*)(Vt + (df * 16 + l15) * 72 + ki * 16 + l4 * 4);
#pragma unroll
        for (int qi = 0; qi < 4; qi++)
          oacc[df][qi] = __builtin_amdgcn_mfma_f32_16x16x16f16(
              av, pb[qi], oacc[df][qi], 0, 0, 0);
      }
    }
  }

  float inv[4];
#pragma unroll
  for (int qi = 0; qi < 4; qi++) {
    float l = lrow[qi];
    l += __shfl_xor(l, 16, 64);
    l += __shfl_xor(l, 32, 64);
    inv[qi] = 1.f / l;
  }
#pragma unroll
  for (int qi = 0; qi < 4; qi++) {
    const int q = q0 + qi * 16 + l15;
    if (q < NQTOK) {
      f16* op = o16 + ((size_t)(b * NQTOK + q)) * CDIM + h * 64 + l4 * 4;
#pragma unroll
      for (int df = 0; df < 4; df++) {
        f16x4_t ov = {(f16)(oacc[df][qi][0] * inv[qi]),
                      (f16)(oacc[df][qi][1] * inv[qi]),
                      (f16)(oacc[df][qi][2] * inv[qi]),
                      (f16)(oacc[df][qi][3] * inv[qi])};
        *(f16x4_t*)(op + df * 16) = ov;
      }
    }
  }
}

// ---------------------------------------------------------------------------
extern "C" void kernel_launch(void* const* d_in, const int* in_sizes, int n_in,
                              void* d_out, int out_size, void* d_ws, size_t ws_size,
                              hipStream_t stream) {
  const float* x      = (const float*)d_in[0];
  const float* cls    = (const float*)d_in[1];
  const float* Wq     = (const float*)d_in[2];
  const float* bq     = (const float*)d_in[3];
  const float* Wk     = (const float*)d_in[4];
  const float* bk     = (const float*)d_in[5];
  const float* Wv     = (const float*)d_in[6];
  const float* bv     = (const float*)d_in[7];
  const float* conv_q = (const float*)d_in[8];
  const float* conv_k = (const float*)d_in[9];
  const float* conv_v = (const float*)d_in[10];
  const float* lnq_w  = (const float*)d_in[11];
  const float* lnq_b  = (const float*)d_in[12];
  const float* lnk_w  = (const float*)d_in[13];
  const float* lnk_b  = (const float*)d_in[14];
  const float* lnv_w  = (const float*)d_in[15];
  const float* lnv_b  = (const float*)d_in[16];
  const float* Wproj  = (const float*)d_in[17];
  const float* bproj  = (const float*)d_in[18];

  // Workspace layout (bytes). Total = 124,747,776 B ≈ 124.7 MB.
  char* wsb = (char*)d_ws;
  f16*   Xt     = (f16*)(wsb + 0);           // 8*1792*768*2 = 22,020,096
  f16*   W16    = (f16*)(wsb + 22020096);    //  4,718,592
  f16*   q_lin  = (f16*)(wsb + 26738688);    // 8*768*1576*2 = 19,365,888
  f16*   k_lin  = (f16*)(wsb + 46104576);    // 19,365,888
  f16*   v_lin  = (f16*)(wsb + 65470464);    // 19,365,888
  f16*   k_pool = (f16*)(wsb + 84836352);    //  4,816,896
  f16*   v_pool = (f16*)(wsb + 89653248);    //  4,816,896
  f16*   Kh     = (f16*)(wsb + 94470144);    //  5,505,024
  f16*   Vht    = (f16*)(wsb + 99975168);    //  5,505,024
  f16*   q_pool = (f16*)(wsb + 105480192);   // 19,267,584 -> end 124,747,776
  f16*   Qh     = Xt;      // alias: Xt dead after QKV GEMM (sizes equal)
  f16*   o16    = v_lin;   // alias: v_lin (+294KB of dead k_pool) at proj;
                           // attn writes only rows < 12552

  f16* W16p = W16 + (size_t)3 * WELEM;

  // 1. convert weights to fp16
  convert4_kernel<<<dim3(576, 4), 256, 0, stream>>>(Wq, Wk, Wv, Wproj, W16);

  // 2. transpose+convert X (+cls as row 1568) -> Xt
  transpose_x_kernel<<<dim3(56, 24, BATCH), 256, 0, stream>>>(x, cls, Xt);

  // 3. fused QKV MFMA GEMM -> f16 lin buffers (stride 1576, col 1568 = cls)
  gemm_qkv_f16_kernel<<<1008, 256, 0, stream>>>(W16, Xt, bq, bk, bv, q_lin);

  // 4. cls rows of Qh/Kh (after qkv, before anything clobbers Xt alias)
  cls_fill_kernel<<<BATCH, 768, 0, stream>>>(q_lin, k_lin, Qh, Kh);

  // 5. all three depthwise convs in one launch (q_pool is its own buffer)
  dwconv3_kernel<<<dim3(BATCH * CDIM, 3), 256, 0, stream>>>(
      q_lin, k_lin, v_lin, conv_q, conv_k, conv_v, q_pool, k_pool, v_pool);

  // 6. fused LN + pack (q and k in one launch; v separate)
  ln_pack_qk2_kernel<<<dim3(62, BATCH), 256, 0, stream>>>(
      q_pool, k_pool, lnq_w, lnq_b, lnk_w, lnk_b, Qh, Kh);
  ln_pack_v_kernel<<<dim3(14, BATCH), 256, 0, stream>>>(v_pool, v_lin, lnv_w,
                                                        lnv_b, Vht);

  // 7. MFMA attention (64-q wave tiles) -> o16
  attn_mfma_kernel<<<dim3(7, NHEADS, BATCH), 256, 0, stream>>>(Qh, Kh, Vht,
                                                               o16);

  // 8. projection MFMA GEMM -> d_out
  float* xo = (float*)d_out;
  float* cls_o = (float*)d_out + (size_t)BATCH * CDIM * NSP;
  gemm_proj_f16_kernel<<<300, 256, 0, stream>>>(W16p, o16, bproj, xo, cls_o);
}